// Round 6
// baseline (565.095 us; speedup 1.0000x reference)
//
#include <hip/hip_runtime.h>
#include <stdint.h>

#define BB 8
#define TTN 4096
#define CCH 32
#define WIN 128
#define KEEP_LT9 3435974144u   // keep iff bits < this  (== 6710887 << 9; uniform < 0.8f)

__device__ __forceinline__ uint32_t rotl32(uint32_t x, int r) {
    return (x << r) | (x >> (32 - r));
}

// threefry2x32, 20 rounds, key fixed to (0, 42) == jax.random.key(42)
__device__ __forceinline__ void threefry2x32_k042(uint32_t x0, uint32_t x1,
                                                  uint32_t& o0, uint32_t& o1) {
    const uint32_t k0 = 0u, k1 = 42u;
    const uint32_t k2 = 0u ^ 42u ^ 0x1BD11BDAu;
    x0 += k0; x1 += k1;
#define TFR(r) { x0 += x1; x1 = rotl32(x1, (r)); x1 ^= x0; }
    TFR(13) TFR(15) TFR(26) TFR(6)
    x0 += k1; x1 += k2 + 1u;
    TFR(17) TFR(29) TFR(16) TFR(24)
    x0 += k2; x1 += k0 + 2u;
    TFR(13) TFR(15) TFR(26) TFR(6)
    x0 += k0; x1 += k1 + 3u;
    TFR(17) TFR(29) TFR(16) TFR(24)
    x0 += k1; x1 += k2 + 4u;
    TFR(13) TFR(15) TFR(26) TFR(6)
    x0 += k2; x1 += k0 + 5u;
#undef TFR
    o0 = x0; o1 = x1;
}

// partitionable threefry: bits(i) = o0^o1 of threefry(key42, (0, i))
__device__ __forceinline__ uint32_t mask_bits(uint32_t idx) {
    uint32_t o0, o1; threefry2x32_k042(0u, idx, o0, o1); return o0 ^ o1;
}

// ---------------- projections: q = (x @ Wq^T) * 1/sqrt(32), k, v ----------------
__global__ __launch_bounds__(256) void proj_qkv(const float* __restrict__ x,
                                                const float* __restrict__ Wq,
                                                const float* __restrict__ Wk,
                                                const float* __restrict__ Wv,
                                                float* __restrict__ Q,
                                                float* __restrict__ K,
                                                float* __restrict__ V) {
    __shared__ float sW[3][CCH * CCH];
    const int tid = threadIdx.x;
    for (int i = tid; i < CCH * CCH; i += 256) {
        sW[0][i] = Wq[i]; sW[1][i] = Wk[i]; sW[2][i] = Wv[i];
    }
    __syncthreads();
    const int row = blockIdx.x * 256 + tid;     // b*T + t
    const float4* xp = reinterpret_cast<const float4*>(x + (size_t)row * CCH);
    float xr[CCH];
    #pragma unroll
    for (int i = 0; i < 8; ++i) {
        float4 t4 = xp[i];
        xr[4*i] = t4.x; xr[4*i+1] = t4.y; xr[4*i+2] = t4.z; xr[4*i+3] = t4.w;
    }
    const float scale = 0.17677669529663687f;   // 1/sqrt(32)
    for (int mtx = 0; mtx < 3; ++mtx) {
        float* op_base = (mtx == 0) ? Q : ((mtx == 1) ? K : V);
        float o[CCH];
        #pragma unroll
        for (int d = 0; d < CCH; ++d) {
            float s0 = 0.f, s1 = 0.f, s2 = 0.f, s3 = 0.f;
            #pragma unroll
            for (int c = 0; c < CCH; c += 4) {
                s0 += xr[c]   * sW[mtx][d*CCH + c];
                s1 += xr[c+1] * sW[mtx][d*CCH + c+1];
                s2 += xr[c+2] * sW[mtx][d*CCH + c+2];
                s3 += xr[c+3] * sW[mtx][d*CCH + c+3];
            }
            o[d] = (s0 + s1) + (s2 + s3);
            if (mtx == 0) o[d] *= scale;
        }
        float4* op = reinterpret_cast<float4*>(op_base + (size_t)row * CCH);
        #pragma unroll
        for (int i = 0; i < 8; ++i)
            op[i] = make_float4(o[4*i], o[4*i+1], o[4*i+2], o[4*i+3]);
    }
}

// merge partial (m2,l2,acc2) into (m,l,acc); no-op when l2==0 (avoids inf-inf NaN)
__device__ __forceinline__ void merge_partial(float& m, float& l, float* acc,
                                              float m2, float l2, const float* acc2) {
    if (l2 > 0.f) {
        const float mn = fmaxf(m, m2);
        const float ca = __expf(m - mn);
        const float cb = __expf(m2 - mn);
        l = l * ca + l2 * cb;
        #pragma unroll
        for (int c = 0; c < CCH; ++c) acc[c] = acc[c] * ca + acc2[c] * cb;
        m = mn;
    }
}

// ---------------- fused causal attention, LDS-staged K/V windows ----------------
// Block = (batch b, 32-row q-tile); b = blockIdx&7 -> per-XCD K/V L2 locality.
// 8 waves x 2 halves = 16 s-slices of 8 within each 128-wide staged window.
// Staging: async split (issue loads -> compute -> ds_write -> barrier), double-
// buffered 64KB LDS. Chunk-fused inner loop (no kr[]/vr[] arrays), live ~110.
// __launch_bounds__(512,3): reg cap ~170 so the live set stays in ARCH VGPRs —
// (512,4)'s 128-cap made the compiler split 64V+64A and pay accvgpr copies.
__global__ __launch_bounds__(512, 3) void attn_fused(const float* __restrict__ Q,
                                                     const float* __restrict__ K,
                                                     const float* __restrict__ V,
                                                     float* __restrict__ out) {
    __shared__ __align__(16) float smem[16384];   // 64 KB

    const int j = blockIdx.x;                   // 0..1023
    const int b = j & 7;                        // XCD-local batch
    const int u = j >> 3;                       // 0..127
    const int x = u >> 1;                       // 0..63
    const int tile = (u & 1) ? x : (127 - x);   // interleave big/small for balance

    const int w = threadIdx.x >> 6;             // wave 0..7
    const int lane = threadIdx.x & 63;
    const int r = lane & 31;                    // row within tile
    const int half = lane >> 5;
    const int slice = 2 * w + half;             // 0..15
    const int sl8 = slice * 8;                  // slice's local s offset
    const int t = tile * 32 + r;

    const size_t rowoff = ((size_t)b * TTN + t) * CCH;
    const float4* qp = reinterpret_cast<const float4*>(Q + rowoff);
    float q[CCH];
    #pragma unroll
    for (int i = 0; i < 8; ++i) {
        float4 t4 = qp[i];
        q[4*i] = t4.x; q[4*i+1] = t4.y; q[4*i+2] = t4.z; q[4*i+3] = t4.w;
    }
    float acc[CCH];
    #pragma unroll
    for (int i = 0; i < CCH; ++i) acc[i] = 0.f;
    float m = -INFINITY, l = 0.f;

    const uint32_t idx_base = ((uint32_t)b << 24) + ((uint32_t)t << 12);
    const float* Kb = K + (size_t)b * TTN * CCH;
    const float* Vb = V + (size_t)b * TTN * CCH;

    const int nwin = (32 * tile + 159) >> 7;    // windows to cover s <= 32*tile+31
    const int diagmax = 32 * (tile & 3) + 31;   // diagonal's local s in tail window

    // staging registers (4 x 16B per wave per window: 2 K-chunks + 2 V-chunks)
    float4 sg0, sg1, sg2, sg3;
    const int c0 = w * 256 + lane * 4;          // chunk float offsets in 4096-float buf
    const int c1 = (w + 8) * 256 + lane * 4;

#define ISSUE_LOADS(S0)                                                        \
    {                                                                          \
        const float* gk = Kb + (size_t)(S0) * CCH;                             \
        const float* gv = Vb + (size_t)(S0) * CCH;                             \
        sg0 = *reinterpret_cast<const float4*>(gk + c0);                       \
        sg1 = *reinterpret_cast<const float4*>(gk + c1);                       \
        sg2 = *reinterpret_cast<const float4*>(gv + c0);                       \
        sg3 = *reinterpret_cast<const float4*>(gv + c1);                       \
    }
#define WRITE_LDS(DBUF)                                                        \
    {                                                                          \
        float* dk = smem + (DBUF) * 4096;                                      \
        float* dv = smem + 8192 + (DBUF) * 4096;                               \
        *reinterpret_cast<float4*>(dk + c0) = sg0;                             \
        *reinterpret_cast<float4*>(dk + c1) = sg1;                             \
        *reinterpret_cast<float4*>(dv + c0) = sg2;                             \
        *reinterpret_cast<float4*>(dv + c1) = sg3;                             \
    }

// one (t,s) cell: dot fused over K chunks, online-softmax update, acc += pk*V
#define ATT_CELL(KBASE, K_IDX, VALID_EXPR)                                     \
    {                                                                          \
        const float* krow = &smem[(KBASE) + (K_IDX) * 32];                     \
        float d0 = 0.f, d1 = 0.f, d2 = 0.f, d3 = 0.f;                          \
        _Pragma("unroll")                                                      \
        for (int i = 0; i < 8; ++i) {                                          \
            float4 kc = *reinterpret_cast<const float4*>(krow + 4 * i);        \
            d0 = fmaf(q[4*i],   kc.x, d0);                                     \
            d1 = fmaf(q[4*i+1], kc.y, d1);                                     \
            d2 = fmaf(q[4*i+2], kc.z, d2);                                     \
            d3 = fmaf(q[4*i+3], kc.w, d3);                                     \
        }                                                                      \
        const float score = (d0 + d1) + (d2 + d3);                             \
        const uint32_t bits = mask_bits(idx_base + (uint32_t)s);               \
        const bool keep = bits < KEEP_LT9;                                     \
        const bool valid = (VALID_EXPR);                                       \
        if (valid && score > m + 8.0f) {        /* deferred-max rescale */     \
            const float corr = __expf(m - score);                              \
            m = score; l *= corr;                                              \
            _Pragma("unroll")                                                  \
            for (int c = 0; c < CCH; ++c) acc[c] *= corr;                      \
        }                                                                      \
        const float p = valid ? __expf(score - m) : 0.f;                       \
        l += p;                                                                \
        const float pk = keep ? p : 0.f;                                       \
        const float* vrow = krow + 8192;                                       \
        _Pragma("unroll")                                                      \
        for (int i = 0; i < 8; ++i) {                                          \
            float4 vc = *reinterpret_cast<const float4*>(vrow + 4 * i);        \
            acc[4*i]   = fmaf(pk, vc.x, acc[4*i]);                             \
            acc[4*i+1] = fmaf(pk, vc.y, acc[4*i+1]);                           \
            acc[4*i+2] = fmaf(pk, vc.z, acc[4*i+2]);                           \
            acc[4*i+3] = fmaf(pk, vc.w, acc[4*i+3]);                           \
        }                                                                      \
    }

    ISSUE_LOADS(0)
    WRITE_LDS(0)
    __syncthreads();

    int buf = 0;
    // ---- bulk windows: no causal mask in the hot path ----
    for (int win = 0; win < nwin - 1; ++win) {
        const int s0 = win << 7;
        ISSUE_LOADS(s0 + WIN)                   // prefetch next (hidden under compute)
        const int kbase = buf * 4096 + sl8 * 32;
        #pragma unroll 1
        for (int k = 0; k < 8; ++k) {
            const int s = s0 + sl8 + k;
            ATT_CELL(kbase, k, true)
        }
        WRITE_LDS(buf ^ 1)
        __syncthreads();
        buf ^= 1;
    }
    // ---- tail window: causal mask, slices beyond diagonal skip ----
    {
        const int s0 = (nwin - 1) << 7;
        if (sl8 <= diagmax) {
            const int kbase = buf * 4096 + sl8 * 32;
            #pragma unroll 1
            for (int k = 0; k < 8; ++k) {
                const int s = s0 + sl8 + k;
                ATT_CELL(kbase, k, s <= t)
            }
        }
        __syncthreads();                        // K/V reads done before merge aliasing
    }
#undef ATT_CELL
#undef ISSUE_LOADS
#undef WRITE_LDS

    // ---- merge the 16 partials per row (aliases staging LDS) ----
    {
        float m2 = __shfl_xor(m, 32);
        float l2 = __shfl_xor(l, 32);
        float acc2[CCH];
        #pragma unroll
        for (int c = 0; c < CCH; ++c) acc2[c] = __shfl_xor(acc[c], 32);
        merge_partial(m, l, acc, m2, l2, acc2);
    }
    float* mbuf = smem;                         // [4][32][34] floats = 17408 B
    float acc2[CCH]; float m2, l2;
#define PUBLISH(slot)                                                          \
    if (half == 0) {                                                           \
        float* pb = mbuf + ((slot) * 32 + r) * 34;                             \
        pb[0] = m; pb[1] = l;                                                  \
        _Pragma("unroll")                                                      \
        for (int c = 0; c < CCH; ++c) pb[2+c] = acc[c];                        \
    }
#define CONSUME(slot)                                                          \
    {                                                                          \
        const float* pb = mbuf + ((slot) * 32 + r) * 34;                       \
        m2 = pb[0]; l2 = pb[1];                                                \
        _Pragma("unroll")                                                      \
        for (int c = 0; c < CCH; ++c) acc2[c] = pb[2+c];                       \
        merge_partial(m, l, acc, m2, l2, acc2);                                \
    }
    if (w >= 4) PUBLISH(w - 4)
    __syncthreads();
    if (w < 4) CONSUME(w)
    __syncthreads();
    if (w == 2 || w == 3) PUBLISH(w - 2)
    __syncthreads();
    if (w < 2) CONSUME(w)
    __syncthreads();
    if (w == 1) PUBLISH(0)
    __syncthreads();
    if (w == 0) {
        CONSUME(0)
        if (half == 0) {
            const float inv = 1.0f / (0.8f * l);
            float4* op = reinterpret_cast<float4*>(out + rowoff);
            #pragma unroll
            for (int i = 0; i < 8; ++i)
                op[i] = make_float4(acc[4*i]*inv, acc[4*i+1]*inv,
                                    acc[4*i+2]*inv, acc[4*i+3]*inv);
        }
    }
#undef PUBLISH
#undef CONSUME
}

extern "C" void kernel_launch(void* const* d_in, const int* in_sizes, int n_in,
                              void* d_out, int out_size, void* d_ws, size_t ws_size,
                              hipStream_t stream) {
    const float* x  = (const float*)d_in[0];
    const float* Wq = (const float*)d_in[1];
    const float* Wk = (const float*)d_in[2];
    const float* Wv = (const float*)d_in[3];
    float* outp = (float*)d_out;

    float* Qw = (float*)d_ws;
    float* Kw = Qw + (size_t)BB * TTN * CCH;
    float* Vw = Kw + (size_t)BB * TTN * CCH;

    proj_qkv<<<(BB * TTN) / 256, 256, 0, stream>>>(x, Wq, Wk, Wv, Qw, Kw, Vw);
    attn_fused<<<1024, 512, 0, stream>>>(Qw, Kw, Vw, outp);
}

// Round 7
// 392.643 us; speedup vs baseline: 1.4392x; 1.4392x over previous
//
#include <hip/hip_runtime.h>
#include <stdint.h>

#define BB 8
#define TTN 4096
#define CCH 32
#define WIN 128
#define KEEP_LT9 3435974144u   // keep iff bits < this  (== 6710887 << 9; uniform < 0.8f)

__device__ __forceinline__ uint32_t rotl32(uint32_t x, int r) {
    return (x << r) | (x >> (32 - r));
}

// threefry2x32, 20 rounds, key fixed to (0, 42) == jax.random.key(42)
__device__ __forceinline__ void threefry2x32_k042(uint32_t x0, uint32_t x1,
                                                  uint32_t& o0, uint32_t& o1) {
    const uint32_t k0 = 0u, k1 = 42u;
    const uint32_t k2 = 0u ^ 42u ^ 0x1BD11BDAu;
    x0 += k0; x1 += k1;
#define TFR(r) { x0 += x1; x1 = rotl32(x1, (r)); x1 ^= x0; }
    TFR(13) TFR(15) TFR(26) TFR(6)
    x0 += k1; x1 += k2 + 1u;
    TFR(17) TFR(29) TFR(16) TFR(24)
    x0 += k2; x1 += k0 + 2u;
    TFR(13) TFR(15) TFR(26) TFR(6)
    x0 += k0; x1 += k1 + 3u;
    TFR(17) TFR(29) TFR(16) TFR(24)
    x0 += k1; x1 += k2 + 4u;
    TFR(13) TFR(15) TFR(26) TFR(6)
    x0 += k2; x1 += k0 + 5u;
#undef TFR
    o0 = x0; o1 = x1;
}

__device__ __forceinline__ uint32_t mask_bits(uint32_t idx) {
    uint32_t o0, o1; threefry2x32_k042(0u, idx, o0, o1); return o0 ^ o1;
}

// ---------------- dropout-mask pre-pass: 1 bit per (b,t,s) cell ----------------
// idx = (b<<24)|(t<<12)|s is the flat JAX mask index. One thread per cell;
// __ballot packs 64 keep-bits; lanes 0/32 store the two words. Whole waves
// above the causal diagonal exit early. Block->batch = blockIdx&7 (XCD-local).
__global__ __launch_bounds__(256) void mask_pass(uint32_t* __restrict__ mw) {
    const int j = blockIdx.x;
    const uint32_t b = (uint32_t)(j & 7);
    const uint32_t idx = (b << 24) + (uint32_t)(j >> 3) * 256u + threadIdx.x;
    const uint32_t t = (idx >> 12) & 4095u;
    const uint32_t s_w = (idx & 4095u) & ~63u;        // wave-uniform window start
    if (s_w > t) return;                              // fully beyond diagonal
    const bool keep = mask_bits(idx) < KEEP_LT9;
    const unsigned long long bal = __ballot(keep);    // bit i = lane i
    const int lane = threadIdx.x & 63;
    if (lane == 0)       mw[idx >> 5] = (uint32_t)bal;
    else if (lane == 32) mw[idx >> 5] = (uint32_t)(bal >> 32);
}

// ---------------- projections: q = (x @ Wq^T) * 1/sqrt(32), k, v ----------------
__global__ __launch_bounds__(256) void proj_qkv(const float* __restrict__ x,
                                                const float* __restrict__ Wq,
                                                const float* __restrict__ Wk,
                                                const float* __restrict__ Wv,
                                                float* __restrict__ Q,
                                                float* __restrict__ K,
                                                float* __restrict__ V) {
    __shared__ float sW[3][CCH * CCH];
    const int tid = threadIdx.x;
    for (int i = tid; i < CCH * CCH; i += 256) {
        sW[0][i] = Wq[i]; sW[1][i] = Wk[i]; sW[2][i] = Wv[i];
    }
    __syncthreads();
    const int row = blockIdx.x * 256 + tid;     // b*T + t
    const float4* xp = reinterpret_cast<const float4*>(x + (size_t)row * CCH);
    float xr[CCH];
    #pragma unroll
    for (int i = 0; i < 8; ++i) {
        float4 t4 = xp[i];
        xr[4*i] = t4.x; xr[4*i+1] = t4.y; xr[4*i+2] = t4.z; xr[4*i+3] = t4.w;
    }
    const float scale = 0.17677669529663687f;   // 1/sqrt(32)
    for (int mtx = 0; mtx < 3; ++mtx) {
        float* op_base = (mtx == 0) ? Q : ((mtx == 1) ? K : V);
        float o[CCH];
        #pragma unroll
        for (int d = 0; d < CCH; ++d) {
            float s0 = 0.f, s1 = 0.f, s2 = 0.f, s3 = 0.f;
            #pragma unroll
            for (int c = 0; c < CCH; c += 4) {
                s0 += xr[c]   * sW[mtx][d*CCH + c];
                s1 += xr[c+1] * sW[mtx][d*CCH + c+1];
                s2 += xr[c+2] * sW[mtx][d*CCH + c+2];
                s3 += xr[c+3] * sW[mtx][d*CCH + c+3];
            }
            o[d] = (s0 + s1) + (s2 + s3);
            if (mtx == 0) o[d] *= scale;
        }
        float4* op = reinterpret_cast<float4*>(op_base + (size_t)row * CCH);
        #pragma unroll
        for (int i = 0; i < 8; ++i)
            op[i] = make_float4(o[4*i], o[4*i+1], o[4*i+2], o[4*i+3]);
    }
}

// merge partial (m2,l2,acc2) into (m,l,acc); no-op when l2==0 (avoids inf-inf NaN)
__device__ __forceinline__ void merge_partial(float& m, float& l, float* acc,
                                              float m2, float l2, const float* acc2) {
    if (l2 > 0.f) {
        const float mn = fmaxf(m, m2);
        const float ca = __expf(m - mn);
        const float cb = __expf(m2 - mn);
        l = l * ca + l2 * cb;
        #pragma unroll
        for (int c = 0; c < CCH; ++c) acc[c] = acc[c] * ca + acc2[c] * cb;
        m = mn;
    }
}

// ---------------- fused causal attention, LDS-staged K/V windows ----------------
// Block = (batch b = j&7 -> XCD-local K/V, 32-row q-tile), LPT order (big first).
// 8 waves x 2 halves = 16 s-slices of 8 per 128-wide staged window; K-row LDS
// reads are half-wave-uniform (broadcast, ~free BW). PRE=1: dropout bits from
// the precomputed bit-array (word prefetched per window); PRE=0: inline threefry.
template<int PRE>
__global__ __launch_bounds__(512, 4) void attn_fused(const float* __restrict__ Q,
                                                     const float* __restrict__ K,
                                                     const float* __restrict__ V,
                                                     const uint32_t* __restrict__ MW,
                                                     float* __restrict__ out) {
    __shared__ __align__(16) float smem[16384];   // 64 KB

    const int j = blockIdx.x;                   // 0..1023
    const int b = j & 7;                        // XCD-local batch
    const int tile = 127 - (j >> 3);            // LPT: biggest tiles dispatched first

    const int w = threadIdx.x >> 6;             // wave 0..7
    const int lane = threadIdx.x & 63;
    const int r = lane & 31;                    // row within tile
    const int half = lane >> 5;
    const int slice = 2 * w + half;             // 0..15
    const int sl8 = slice * 8;                  // slice's local s offset
    const int t = tile * 32 + r;

    const size_t rowoff = ((size_t)b * TTN + t) * CCH;
    const float4* qp = reinterpret_cast<const float4*>(Q + rowoff);
    float q[CCH];
    #pragma unroll
    for (int i = 0; i < 8; ++i) {
        float4 t4 = qp[i];
        q[4*i] = t4.x; q[4*i+1] = t4.y; q[4*i+2] = t4.z; q[4*i+3] = t4.w;
    }
    float acc[CCH];
    #pragma unroll
    for (int i = 0; i < CCH; ++i) acc[i] = 0.f;
    float m = -INFINITY, l = 0.f;

    const uint32_t idx_base = ((uint32_t)b << 24) + ((uint32_t)t << 12);
    const float* Kb = K + (size_t)b * TTN * CCH;
    const float* Vb = V + (size_t)b * TTN * CCH;

    const int nwin = (32 * tile + 159) >> 7;    // windows to cover s <= 32*tile+31
    const int diagmax = 32 * (tile & 3) + 31;   // diagonal's local s in tail window
    const int shbase = sl8 & 31;                // bit offset of this slice in its word

    // staging registers (4 x 16B per wave per window: 2 K-chunks + 2 V-chunks)
    float4 sg0, sg1, sg2, sg3;
    uint32_t mword_cur = 0u, mword_nxt = 0u;
    const int c0 = w * 256 + lane * 4;          // chunk float offsets in 4096-float buf
    const int c1 = (w + 8) * 256 + lane * 4;

#define ISSUE_LOADS(S0)                                                        \
    {                                                                          \
        const float* gk = Kb + (size_t)(S0) * CCH;                             \
        const float* gv = Vb + (size_t)(S0) * CCH;                             \
        sg0 = *reinterpret_cast<const float4*>(gk + c0);                       \
        sg1 = *reinterpret_cast<const float4*>(gk + c1);                       \
        sg2 = *reinterpret_cast<const float4*>(gv + c0);                       \
        sg3 = *reinterpret_cast<const float4*>(gv + c1);                       \
        if (PRE) mword_nxt = MW[(idx_base + (uint32_t)((S0) + sl8)) >> 5];     \
    }
#define WRITE_LDS(DBUF)                                                        \
    {                                                                          \
        float* dk = smem + (DBUF) * 4096;                                      \
        float* dv = smem + 8192 + (DBUF) * 4096;                               \
        *reinterpret_cast<float4*>(dk + c0) = sg0;                             \
        *reinterpret_cast<float4*>(dk + c1) = sg1;                             \
        *reinterpret_cast<float4*>(dv + c0) = sg2;                             \
        *reinterpret_cast<float4*>(dv + c1) = sg3;                             \
    }

// one (t,s) cell: dot fused over K chunks, online-softmax update, acc += pk*V
#define ATT_CELL(KBASE, K_IDX, VALID_EXPR)                                     \
    {                                                                          \
        const float* krow = &smem[(KBASE) + (K_IDX) * 32];                     \
        float d0 = 0.f, d1 = 0.f, d2 = 0.f, d3 = 0.f;                          \
        _Pragma("unroll")                                                      \
        for (int i = 0; i < 8; ++i) {                                          \
            float4 kc = *reinterpret_cast<const float4*>(krow + 4 * i);        \
            d0 = fmaf(q[4*i],   kc.x, d0);                                     \
            d1 = fmaf(q[4*i+1], kc.y, d1);                                     \
            d2 = fmaf(q[4*i+2], kc.z, d2);                                     \
            d3 = fmaf(q[4*i+3], kc.w, d3);                                     \
        }                                                                      \
        const float score = (d0 + d1) + (d2 + d3);                             \
        bool keep;                                                             \
        if (PRE) keep = ((sh >> (K_IDX)) & 1u) != 0u;                          \
        else     keep = mask_bits(idx_base + (uint32_t)s) < KEEP_LT9;          \
        const bool valid = (VALID_EXPR);                                       \
        if (valid && score > m + 8.0f) {        /* deferred-max rescale */     \
            const float corr = __expf(m - score);                              \
            m = score; l *= corr;                                              \
            _Pragma("unroll")                                                  \
            for (int c = 0; c < CCH; ++c) acc[c] *= corr;                      \
        }                                                                      \
        const float p = valid ? __expf(score - m) : 0.f;                       \
        l += p;                                                                \
        const float pk = keep ? p : 0.f;                                       \
        const float* vrow = krow + 8192;                                       \
        _Pragma("unroll")                                                      \
        for (int i = 0; i < 8; ++i) {                                          \
            float4 vc = *reinterpret_cast<const float4*>(vrow + 4 * i);        \
            acc[4*i]   = fmaf(pk, vc.x, acc[4*i]);                             \
            acc[4*i+1] = fmaf(pk, vc.y, acc[4*i+1]);                           \
            acc[4*i+2] = fmaf(pk, vc.z, acc[4*i+2]);                           \
            acc[4*i+3] = fmaf(pk, vc.w, acc[4*i+3]);                           \
        }                                                                      \
    }

    if (PRE) mword_cur = MW[(idx_base + (uint32_t)sl8) >> 5];
    ISSUE_LOADS(0)
    WRITE_LDS(0)
    __syncthreads();
    if (PRE) { uint32_t tmp = mword_cur; mword_cur = mword_nxt; mword_nxt = tmp; }
    // (window-0 ISSUE_LOADS overwrote mword_nxt with window-1's word; swap so
    //  cur = window 0. Harmless when nwin==1.)
    if (PRE) { /* after swap: mword_cur = window0 word? no — fix below */ }

    // NOTE: prologue loaded window0 into mword_cur, then ISSUE_LOADS(0) reloaded
    // window0's word into mword_nxt (S0=0). So cur==nxt==window0 word; the swap
    // above is a no-op in effect. Subsequent windows rotate properly.

    int buf = 0;
    // ---- bulk windows: no causal mask in the hot path ----
    for (int win = 0; win < nwin - 1; ++win) {
        const int s0 = win << 7;
        ISSUE_LOADS(s0 + WIN)                   // prefetch next K/V + next mask word
        const uint32_t sh = PRE ? (mword_cur >> shbase) : 0u;
        const int kbase = buf * 4096 + sl8 * 32;
        #pragma unroll 1
        for (int k = 0; k < 8; ++k) {
            const int s = s0 + sl8 + k;
            (void)s;
            ATT_CELL(kbase, k, true)
        }
        WRITE_LDS(buf ^ 1)
        __syncthreads();
        buf ^= 1;
        if (PRE) mword_cur = mword_nxt;
    }
    // ---- tail window: causal mask, slices beyond diagonal skip ----
    {
        const int s0 = (nwin - 1) << 7;
        if (sl8 <= diagmax) {
            const uint32_t sh = PRE ? (mword_cur >> shbase) : 0u;
            const int kbase = buf * 4096 + sl8 * 32;
            #pragma unroll 1
            for (int k = 0; k < 8; ++k) {
                const int s = s0 + sl8 + k;
                ATT_CELL(kbase, k, s <= t)
            }
        }
        __syncthreads();                        // K/V reads done before merge aliasing
    }
#undef ATT_CELL
#undef ISSUE_LOADS
#undef WRITE_LDS

    // ---- merge the 16 partials per row (aliases staging LDS) ----
    {
        float m2 = __shfl_xor(m, 32);
        float l2 = __shfl_xor(l, 32);
        float acc2[CCH];
        #pragma unroll
        for (int c = 0; c < CCH; ++c) acc2[c] = __shfl_xor(acc[c], 32);
        merge_partial(m, l, acc, m2, l2, acc2);
    }
    float* mbuf = smem;                         // [4][32][34] floats = 17408 B
    float acc2[CCH]; float m2, l2;
#define PUBLISH(slot)                                                          \
    if (half == 0) {                                                           \
        float* pb = mbuf + ((slot) * 32 + r) * 34;                             \
        pb[0] = m; pb[1] = l;                                                  \
        _Pragma("unroll")                                                      \
        for (int c = 0; c < CCH; ++c) pb[2+c] = acc[c];                        \
    }
#define CONSUME(slot)                                                          \
    {                                                                          \
        const float* pb = mbuf + ((slot) * 32 + r) * 34;                       \
        m2 = pb[0]; l2 = pb[1];                                                \
        _Pragma("unroll")                                                      \
        for (int c = 0; c < CCH; ++c) acc2[c] = pb[2+c];                       \
        merge_partial(m, l, acc, m2, l2, acc2);                                \
    }
    if (w >= 4) PUBLISH(w - 4)
    __syncthreads();
    if (w < 4) CONSUME(w)
    __syncthreads();
    if (w == 2 || w == 3) PUBLISH(w - 2)
    __syncthreads();
    if (w < 2) CONSUME(w)
    __syncthreads();
    if (w == 1) PUBLISH(0)
    __syncthreads();
    if (w == 0) {
        CONSUME(0)
        if (half == 0) {
            const float inv = 1.0f / (0.8f * l);
            float4* op = reinterpret_cast<float4*>(out + rowoff);
            #pragma unroll
            for (int i = 0; i < 8; ++i)
                op[i] = make_float4(acc[4*i]*inv, acc[4*i+1]*inv,
                                    acc[4*i+2]*inv, acc[4*i+3]*inv);
        }
    }
#undef PUBLISH
#undef CONSUME
}

extern "C" void kernel_launch(void* const* d_in, const int* in_sizes, int n_in,
                              void* d_out, int out_size, void* d_ws, size_t ws_size,
                              hipStream_t stream) {
    const float* x  = (const float*)d_in[0];
    const float* Wq = (const float*)d_in[1];
    const float* Wk = (const float*)d_in[2];
    const float* Wv = (const float*)d_in[3];
    float* outp = (float*)d_out;

    float* Qw = (float*)d_ws;
    float* Kw = Qw + (size_t)BB * TTN * CCH;
    float* Vw = Kw + (size_t)BB * TTN * CCH;
    const size_t qkv_bytes  = (size_t)3 * BB * TTN * CCH * sizeof(float);   // 12.6 MB
    const size_t mask_bytes = ((size_t)BB * TTN * TTN) / 8;                 // 16.8 MB
    uint32_t* MW = (uint32_t*)((char*)d_ws + qkv_bytes);

    proj_qkv<<<(BB * TTN) / 256, 256, 0, stream>>>(x, Wq, Wk, Wv, Qw, Kw, Vw);
    if (ws_size >= qkv_bytes + mask_bytes) {
        mask_pass<<<(BB * TTN * (TTN / 256)), 256, 0, stream>>>(MW);
        attn_fused<1><<<1024, 512, 0, stream>>>(Qw, Kw, Vw, MW, outp);
    } else {
        attn_fused<0><<<1024, 512, 0, stream>>>(Qw, Kw, Vw, nullptr, outp);
    }
}

// Round 8
// 381.723 us; speedup vs baseline: 1.4804x; 1.0286x over previous
//
#include <hip/hip_runtime.h>
#include <stdint.h>

#define BB 8
#define TTN 4096
#define CCH 32
#define WIN 128
#define KEEP_LT9 3435974144u   // keep iff bits < this  (== 6710887 << 9; uniform < 0.8f)

typedef __attribute__((ext_vector_type(2))) float f32x2;

// packed fp32 FMA: d = a*b + c elementwise on 2-wide pairs (VOP3P, 1 inst)
__device__ __forceinline__ f32x2 pk_fma(f32x2 a, f32x2 b, f32x2 c) {
    f32x2 d;
    asm("v_pk_fma_f32 %0, %1, %2, %3" : "=v"(d) : "v"(a), "v"(b), "v"(c));
    return d;
}

__device__ __forceinline__ uint32_t rotl32(uint32_t x, int r) {
    return (x << r) | (x >> (32 - r));
}

// threefry2x32, 20 rounds, key fixed to (0, 42) == jax.random.key(42)
__device__ __forceinline__ void threefry2x32_k042(uint32_t x0, uint32_t x1,
                                                  uint32_t& o0, uint32_t& o1) {
    const uint32_t k0 = 0u, k1 = 42u;
    const uint32_t k2 = 0u ^ 42u ^ 0x1BD11BDAu;
    x0 += k0; x1 += k1;
#define TFR(r) { x0 += x1; x1 = rotl32(x1, (r)); x1 ^= x0; }
    TFR(13) TFR(15) TFR(26) TFR(6)
    x0 += k1; x1 += k2 + 1u;
    TFR(17) TFR(29) TFR(16) TFR(24)
    x0 += k2; x1 += k0 + 2u;
    TFR(13) TFR(15) TFR(26) TFR(6)
    x0 += k0; x1 += k1 + 3u;
    TFR(17) TFR(29) TFR(16) TFR(24)
    x0 += k1; x1 += k2 + 4u;
    TFR(13) TFR(15) TFR(26) TFR(6)
    x0 += k2; x1 += k0 + 5u;
#undef TFR
    o0 = x0; o1 = x1;
}

__device__ __forceinline__ uint32_t mask_bits(uint32_t idx) {
    uint32_t o0, o1; threefry2x32_k042(0u, idx, o0, o1); return o0 ^ o1;
}

// ---------------- dropout-mask pre-pass (triangle-only, persistent blocks) ----------------
// 2048 blocks x 256 thr (8 blocks/CU, reg-light -> 32 waves/CU). Block handles
// row-PAIRS (rr, 32767-rr): per-pair cell count is a constant 4096 -> balanced.
// Per row, threads sweep s in 256-chunks up to t|63; __ballot packs 64 bits;
// per-wave iteration counts are uniform ((t|63)+1 is a multiple of 64).
__global__ __launch_bounds__(256) void mask_pass(uint32_t* __restrict__ mw) {
    for (int rr = blockIdx.x; rr < 16384; rr += 2048) {
        #pragma unroll
        for (int pair = 0; pair < 2; ++pair) {
            const int row = pair ? (32767 - rr) : rr;
            const uint32_t b = (uint32_t)(row >> 12);
            const uint32_t t = (uint32_t)(row & 4095);
            const uint32_t base = (b << 24) | (t << 12);
            const uint32_t smax = t | 63u;
            for (uint32_t s = threadIdx.x; s <= smax; s += 256) {
                const bool keep = mask_bits(base + s) < KEEP_LT9;
                const unsigned long long bal = __ballot(keep);
                const int lane = threadIdx.x & 63;
                const uint32_t idx = base + s;
                if (lane == 0)       mw[idx >> 5] = (uint32_t)bal;
                else if (lane == 32) mw[idx >> 5] = (uint32_t)(bal >> 32);
            }
        }
    }
}

// ---------------- projections: q = (x @ Wq^T) * 1/sqrt(32), k, v ----------------
__global__ __launch_bounds__(256) void proj_qkv(const float* __restrict__ x,
                                                const float* __restrict__ Wq,
                                                const float* __restrict__ Wk,
                                                const float* __restrict__ Wv,
                                                float* __restrict__ Q,
                                                float* __restrict__ K,
                                                float* __restrict__ V) {
    __shared__ float sW[3][CCH * CCH];
    const int tid = threadIdx.x;
    for (int i = tid; i < CCH * CCH; i += 256) {
        sW[0][i] = Wq[i]; sW[1][i] = Wk[i]; sW[2][i] = Wv[i];
    }
    __syncthreads();
    const int row = blockIdx.x * 256 + tid;     // b*T + t
    const float4* xp = reinterpret_cast<const float4*>(x + (size_t)row * CCH);
    float xr[CCH];
    #pragma unroll
    for (int i = 0; i < 8; ++i) {
        float4 t4 = xp[i];
        xr[4*i] = t4.x; xr[4*i+1] = t4.y; xr[4*i+2] = t4.z; xr[4*i+3] = t4.w;
    }
    const float scale = 0.17677669529663687f;   // 1/sqrt(32)
    for (int mtx = 0; mtx < 3; ++mtx) {
        float* op_base = (mtx == 0) ? Q : ((mtx == 1) ? K : V);
        float o[CCH];
        #pragma unroll
        for (int d = 0; d < CCH; ++d) {
            float s0 = 0.f, s1 = 0.f, s2 = 0.f, s3 = 0.f;
            #pragma unroll
            for (int c = 0; c < CCH; c += 4) {
                s0 += xr[c]   * sW[mtx][d*CCH + c];
                s1 += xr[c+1] * sW[mtx][d*CCH + c+1];
                s2 += xr[c+2] * sW[mtx][d*CCH + c+2];
                s3 += xr[c+3] * sW[mtx][d*CCH + c+3];
            }
            o[d] = (s0 + s1) + (s2 + s3);
            if (mtx == 0) o[d] *= scale;
        }
        float4* op = reinterpret_cast<float4*>(op_base + (size_t)row * CCH);
        #pragma unroll
        for (int i = 0; i < 8; ++i)
            op[i] = make_float4(o[4*i], o[4*i+1], o[4*i+2], o[4*i+3]);
    }
}

// merge partial (m2,l2,acc2) into (m,l,acc); no-op when l2==0 (avoids inf-inf NaN)
__device__ __forceinline__ void merge_partial(float& m, float& l, float* acc,
                                              float m2, float l2, const float* acc2) {
    if (l2 > 0.f) {
        const float mn = fmaxf(m, m2);
        const float ca = __expf(m - mn);
        const float cb = __expf(m2 - mn);
        l = l * ca + l2 * cb;
        #pragma unroll
        for (int c = 0; c < CCH; ++c) acc[c] = acc[c] * ca + acc2[c] * cb;
        m = mn;
    }
}

// ---------------- fused causal attention, LDS-staged K/V windows ----------------
// Block = (batch b = j&7 -> XCD-local K/V, 32-row q-tile), LPT order (big first).
// 8 waves x 2 halves = 16 s-slices of 8 per 128-wide staged window; K/V LDS reads
// are half-wave broadcast. Inner math uses v_pk_fma_f32 (2 FLOP-pairs/inst):
// dot = 16 pk_fma, PV = 16 pk_fma (vs 64 scalar FMA). Dropout bits from the
// precomputed bit-array (PRE=1) with per-window word prefetch; PRE=0 = inline.
template<int PRE>
__global__ __launch_bounds__(512, 4) void attn_fused(const float* __restrict__ Q,
                                                     const float* __restrict__ K,
                                                     const float* __restrict__ V,
                                                     const uint32_t* __restrict__ MW,
                                                     float* __restrict__ out) {
    __shared__ __align__(16) float smem[16384];   // 64 KB

    const int j = blockIdx.x;                   // 0..1023
    const int b = j & 7;                        // XCD-local batch
    const int tile = 127 - (j >> 3);            // LPT: biggest tiles first

    const int w = threadIdx.x >> 6;             // wave 0..7
    const int lane = threadIdx.x & 63;
    const int r = lane & 31;                    // row within tile
    const int half = lane >> 5;
    const int slice = 2 * w + half;             // 0..15
    const int sl8 = slice * 8;                  // slice's local s offset
    const int t = tile * 32 + r;

    const size_t rowoff = ((size_t)b * TTN + t) * CCH;
    const float4* qp = reinterpret_cast<const float4*>(Q + rowoff);
    f32x2 q2[16];
    float* qf = reinterpret_cast<float*>(q2);
    #pragma unroll
    for (int i = 0; i < 8; ++i) {
        float4 t4 = qp[i];
        qf[4*i] = t4.x; qf[4*i+1] = t4.y; qf[4*i+2] = t4.z; qf[4*i+3] = t4.w;
    }
    f32x2 av[16];
    float* accf = reinterpret_cast<float*>(av);
    #pragma unroll
    for (int i = 0; i < 16; ++i) av[i] = (f32x2){0.f, 0.f};
    float m = -INFINITY, l = 0.f;

    const uint32_t idx_base = ((uint32_t)b << 24) + ((uint32_t)t << 12);
    const float* Kb = K + (size_t)b * TTN * CCH;
    const float* Vb = V + (size_t)b * TTN * CCH;

    const int nwin = (32 * tile + 159) >> 7;    // windows covering s <= 32*tile+31
    const int diagmax = 32 * (tile & 3) + 31;   // diagonal's local s in tail window
    const int shbase = sl8 & 31;                // bit offset of slice in its word

    float4 sg0, sg1, sg2, sg3;                  // staging regs (2 K + 2 V chunks)
    uint32_t mword_cur = 0u, mword_nxt = 0u;
    const int c0 = w * 256 + lane * 4;          // chunk offsets in 4096-float buf
    const int c1 = (w + 8) * 256 + lane * 4;

#define ISSUE_LOADS(S0)                                                        \
    {                                                                          \
        const float* gk = Kb + (size_t)(S0) * CCH;                             \
        const float* gv = Vb + (size_t)(S0) * CCH;                             \
        sg0 = *reinterpret_cast<const float4*>(gk + c0);                       \
        sg1 = *reinterpret_cast<const float4*>(gk + c1);                       \
        sg2 = *reinterpret_cast<const float4*>(gv + c0);                       \
        sg3 = *reinterpret_cast<const float4*>(gv + c1);                       \
        if (PRE) mword_nxt = MW[(idx_base + (uint32_t)((S0) + sl8)) >> 5];     \
    }
#define WRITE_LDS(DBUF)                                                        \
    {                                                                          \
        float* dk = smem + (DBUF) * 4096;                                      \
        float* dv = smem + 8192 + (DBUF) * 4096;                               \
        *reinterpret_cast<float4*>(dk + c0) = sg0;                             \
        *reinterpret_cast<float4*>(dk + c1) = sg1;                             \
        *reinterpret_cast<float4*>(dv + c0) = sg2;                             \
        *reinterpret_cast<float4*>(dv + c1) = sg3;                             \
    }

// one (t,s) cell: packed dot, online-softmax update, packed acc += pk*V
#define ATT_CELL(KBASE, K_IDX, VALID_EXPR)                                     \
    {                                                                          \
        const float* krow = &smem[(KBASE) + (K_IDX) * 32];                     \
        f32x2 da = {0.f, 0.f}, db = {0.f, 0.f};                                \
        _Pragma("unroll")                                                      \
        for (int i = 0; i < 8; ++i) {                                          \
            float4 kc = *reinterpret_cast<const float4*>(krow + 4 * i);        \
            f32x2 ka = {kc.x, kc.y}, kb = {kc.z, kc.w};                        \
            da = pk_fma(q2[2*i],   ka, da);                                    \
            db = pk_fma(q2[2*i+1], kb, db);                                    \
        }                                                                      \
        f32x2 dd = da + db;                                                    \
        const float score = dd.x + dd.y;                                       \
        bool keep;                                                             \
        if (PRE) keep = ((sh >> (K_IDX)) & 1u) != 0u;                          \
        else     keep = mask_bits(idx_base + (uint32_t)s) < KEEP_LT9;          \
        const bool valid = (VALID_EXPR);                                       \
        if (valid && score > m + 8.0f) {        /* deferred-max rescale */     \
            const float corr = __expf(m - score);                              \
            m = score; l *= corr;                                              \
            const f32x2 cc = {corr, corr};                                     \
            _Pragma("unroll")                                                  \
            for (int i = 0; i < 16; ++i) av[i] *= cc;                          \
        }                                                                      \
        const float p = valid ? __expf(score - m) : 0.f;                       \
        l += p;                                                                \
        const float pk = keep ? p : 0.f;                                       \
        const f32x2 pp = {pk, pk};                                             \
        const float* vrow = krow + 8192;                                       \
        _Pragma("unroll")                                                      \
        for (int i = 0; i < 8; ++i) {                                          \
            float4 vc = *reinterpret_cast<const float4*>(vrow + 4 * i);        \
            f32x2 va = {vc.x, vc.y}, vb = {vc.z, vc.w};                        \
            av[2*i]   = pk_fma(pp, va, av[2*i]);                               \
            av[2*i+1] = pk_fma(pp, vb, av[2*i+1]);                             \
        }                                                                      \
    }

    ISSUE_LOADS(0)
    WRITE_LDS(0)
    __syncthreads();
    mword_cur = mword_nxt;                      // window-0 word

    int buf = 0;
    // ---- bulk windows: no causal mask in the hot path ----
    for (int win = 0; win < nwin - 1; ++win) {
        const int s0 = win << 7;
        ISSUE_LOADS(s0 + WIN)                   // prefetch next K/V + mask word
        const uint32_t sh = PRE ? (mword_cur >> shbase) : 0u;
        const int kbase = buf * 4096 + sl8 * 32;
        #pragma unroll 1
        for (int k = 0; k < 8; ++k) {
            const int s = s0 + sl8 + k;
            (void)s;
            ATT_CELL(kbase, k, true)
        }
        WRITE_LDS(buf ^ 1)
        __syncthreads();
        buf ^= 1;
        mword_cur = mword_nxt;
    }
    // ---- tail window: causal mask, slices beyond diagonal skip ----
    {
        const int s0 = (nwin - 1) << 7;
        if (sl8 <= diagmax) {
            const uint32_t sh = PRE ? (mword_cur >> shbase) : 0u;
            const int kbase = buf * 4096 + sl8 * 32;
            #pragma unroll 1
            for (int k = 0; k < 8; ++k) {
                const int s = s0 + sl8 + k;
                ATT_CELL(kbase, k, s <= t)
            }
        }
        __syncthreads();                        // K/V reads done before merge aliasing
    }
#undef ATT_CELL
#undef ISSUE_LOADS
#undef WRITE_LDS

    // ---- merge the 16 partials per row (aliases staging LDS) ----
    {
        float m2 = __shfl_xor(m, 32);
        float l2 = __shfl_xor(l, 32);
        float acc2[CCH];
        #pragma unroll
        for (int c = 0; c < CCH; ++c) acc2[c] = __shfl_xor(accf[c], 32);
        merge_partial(m, l, accf, m2, l2, acc2);
    }
    float* mbuf = smem;                         // [4][32][34] floats = 17408 B
    float acc2[CCH]; float m2, l2;
#define PUBLISH(slot)                                                          \
    if (half == 0) {                                                           \
        float* pb = mbuf + ((slot) * 32 + r) * 34;                             \
        pb[0] = m; pb[1] = l;                                                  \
        _Pragma("unroll")                                                      \
        for (int c = 0; c < CCH; ++c) pb[2+c] = accf[c];                       \
    }
#define CONSUME(slot)                                                          \
    {                                                                          \
        const float* pb = mbuf + ((slot) * 32 + r) * 34;                       \
        m2 = pb[0]; l2 = pb[1];                                                \
        _Pragma("unroll")                                                      \
        for (int c = 0; c < CCH; ++c) acc2[c] = pb[2+c];                       \
        merge_partial(m, l, accf, m2, l2, acc2);                               \
    }
    if (w >= 4) PUBLISH(w - 4)
    __syncthreads();
    if (w < 4) CONSUME(w)
    __syncthreads();
    if (w == 2 || w == 3) PUBLISH(w - 2)
    __syncthreads();
    if (w < 2) CONSUME(w)
    __syncthreads();
    if (w == 1) PUBLISH(0)
    __syncthreads();
    if (w == 0) {
        CONSUME(0)
        if (half == 0) {
            const float inv = 1.0f / (0.8f * l);
            float4* op = reinterpret_cast<float4*>(out + rowoff);
            #pragma unroll
            for (int i = 0; i < 8; ++i)
                op[i] = make_float4(accf[4*i]*inv, accf[4*i+1]*inv,
                                    accf[4*i+2]*inv, accf[4*i+3]*inv);
        }
    }
#undef PUBLISH
#undef CONSUME
}

extern "C" void kernel_launch(void* const* d_in, const int* in_sizes, int n_in,
                              void* d_out, int out_size, void* d_ws, size_t ws_size,
                              hipStream_t stream) {
    const float* x  = (const float*)d_in[0];
    const float* Wq = (const float*)d_in[1];
    const float* Wk = (const float*)d_in[2];
    const float* Wv = (const float*)d_in[3];
    float* outp = (float*)d_out;

    float* Qw = (float*)d_ws;
    float* Kw = Qw + (size_t)BB * TTN * CCH;
    float* Vw = Kw + (size_t)BB * TTN * CCH;
    const size_t qkv_bytes  = (size_t)3 * BB * TTN * CCH * sizeof(float);   // 12.6 MB
    const size_t mask_bytes = ((size_t)BB * TTN * TTN) / 8;                 // 16.8 MB
    uint32_t* MW = (uint32_t*)((char*)d_ws + qkv_bytes);

    proj_qkv<<<(BB * TTN) / 256, 256, 0, stream>>>(x, Wq, Wk, Wv, Qw, Kw, Vw);
    if (ws_size >= qkv_bytes + mask_bytes) {
        mask_pass<<<2048, 256, 0, stream>>>(MW);
        attn_fused<1><<<1024, 512, 0, stream>>>(Qw, Kw, Vw, MW, outp);
    } else {
        attn_fused<0><<<1024, 512, 0, stream>>>(Qw, Kw, Vw, nullptr, outp);
    }
}

// Round 9
// 238.894 us; speedup vs baseline: 2.3655x; 1.5979x over previous
//
#include <hip/hip_runtime.h>
#include <stdint.h>

#define BB 8
#define TTN 4096
#define CCH 32
#define WIN 128
#define KEEP_LT9 3435974144u   // keep iff bits < this (uniform < 0.8f)

typedef __attribute__((ext_vector_type(8))) short bf16x8;
typedef __attribute__((ext_vector_type(4))) float f32x4;

union B8 { uint32_t u[4]; uint4 q; bf16x8 v; };

__device__ __forceinline__ uint32_t cvt_pk_bf16(float lo, float hi) {
    uint32_t d;
    asm("v_cvt_pk_bf16_f32 %0, %1, %2" : "=v"(d) : "v"(lo), "v"(hi));
    return d;
}

__device__ __forceinline__ uint32_t rotl32(uint32_t x, int r) {
    return (x << r) | (x >> (32 - r));
}

// threefry2x32, 20 rounds, key (0, 42) == jax.random.key(42)
__device__ __forceinline__ void threefry2x32_k042(uint32_t x0, uint32_t x1,
                                                  uint32_t& o0, uint32_t& o1) {
    const uint32_t k0 = 0u, k1 = 42u;
    const uint32_t k2 = 0u ^ 42u ^ 0x1BD11BDAu;
    x0 += k0; x1 += k1;
#define TFR(r) { x0 += x1; x1 = rotl32(x1, (r)); x1 ^= x0; }
    TFR(13) TFR(15) TFR(26) TFR(6)
    x0 += k1; x1 += k2 + 1u;
    TFR(17) TFR(29) TFR(16) TFR(24)
    x0 += k2; x1 += k0 + 2u;
    TFR(13) TFR(15) TFR(26) TFR(6)
    x0 += k0; x1 += k1 + 3u;
    TFR(17) TFR(29) TFR(16) TFR(24)
    x0 += k1; x1 += k2 + 4u;
    TFR(13) TFR(15) TFR(26) TFR(6)
    x0 += k2; x1 += k0 + 5u;
#undef TFR
    o0 = x0; o1 = x1;
}

__device__ __forceinline__ uint32_t mask_bits(uint32_t idx) {
    uint32_t o0, o1; threefry2x32_k042(0u, idx, o0, o1); return o0 ^ o1;
}

// ---------------- dropout-mask pre-pass, 2 independent threefry chains/thread ----------------
__global__ __launch_bounds__(256) void mask_pass(uint32_t* __restrict__ mw) {
    const int lane = threadIdx.x & 63;
    for (int rr = blockIdx.x; rr < 16384; rr += 2048) {
        #pragma unroll
        for (int pair = 0; pair < 2; ++pair) {
            const int row = pair ? (32767 - rr) : rr;
            const uint32_t base = (((uint32_t)row >> 12) << 24) | (((uint32_t)row & 4095u) << 12);
            const uint32_t smax = ((uint32_t)row & 4095u) | 63u;
            uint32_t s = threadIdx.x;
            for (; s + 256u <= smax; s += 512u) {        // dual-chain: 2 indep threefrys in flight
                const uint32_t i0 = base + s, i1 = base + s + 256u;
                const bool k0 = mask_bits(i0) < KEEP_LT9;
                const bool k1 = mask_bits(i1) < KEEP_LT9;
                const unsigned long long b0 = __ballot(k0);
                const unsigned long long b1 = __ballot(k1);
                if (lane == 0)       { mw[i0 >> 5] = (uint32_t)b0;         mw[i1 >> 5] = (uint32_t)b1; }
                else if (lane == 32) { mw[i0 >> 5] = (uint32_t)(b0 >> 32); mw[i1 >> 5] = (uint32_t)(b1 >> 32); }
            }
            for (; s <= smax; s += 256u) {
                const uint32_t i0 = base + s;
                const bool k0 = mask_bits(i0) < KEEP_LT9;
                const unsigned long long b0 = __ballot(k0);
                if (lane == 0)       mw[i0 >> 5] = (uint32_t)b0;
                else if (lane == 32) mw[i0 >> 5] = (uint32_t)(b0 >> 32);
            }
        }
    }
}

// ---------------- projections: Q fp32 (scaled), K bf16 row-major, V bf16 TRANSPOSED ----------------
__global__ __launch_bounds__(256) void proj_qkv(const float* __restrict__ x,
                                                const float* __restrict__ Wq,
                                                const float* __restrict__ Wk,
                                                const float* __restrict__ Wv,
                                                float* __restrict__ Qf,
                                                uint16_t* __restrict__ Kb,
                                                uint16_t* __restrict__ Vt) {
    __shared__ float sW[3][CCH * CCH];
    __shared__ uint16_t vs[256][34];            // v bf16, padded row (bank spread)
    const int tid = threadIdx.x;
    for (int i = tid; i < CCH * CCH; i += 256) {
        sW[0][i] = Wq[i]; sW[1][i] = Wk[i]; sW[2][i] = Wv[i];
    }
    __syncthreads();
    const int row = blockIdx.x * 256 + tid;     // b*T + t
    const float4* xp = reinterpret_cast<const float4*>(x + (size_t)row * CCH);
    float xr[CCH];
    #pragma unroll
    for (int i = 0; i < 8; ++i) {
        float4 t4 = xp[i];
        xr[4*i] = t4.x; xr[4*i+1] = t4.y; xr[4*i+2] = t4.z; xr[4*i+3] = t4.w;
    }
    const float scale = 0.17677669529663687f;   // 1/sqrt(32)
    #pragma unroll
    for (int mtx = 0; mtx < 3; ++mtx) {
        float o[CCH];
        #pragma unroll
        for (int d = 0; d < CCH; ++d) {
            float s0 = 0.f, s1 = 0.f, s2 = 0.f, s3 = 0.f;
            #pragma unroll
            for (int c = 0; c < CCH; c += 4) {
                s0 += xr[c]   * sW[mtx][d*CCH + c];
                s1 += xr[c+1] * sW[mtx][d*CCH + c+1];
                s2 += xr[c+2] * sW[mtx][d*CCH + c+2];
                s3 += xr[c+3] * sW[mtx][d*CCH + c+3];
            }
            o[d] = (s0 + s1) + (s2 + s3);
            if (mtx == 0) o[d] *= scale;
        }
        if (mtx == 0) {
            float4* op = reinterpret_cast<float4*>(Qf + (size_t)row * CCH);
            #pragma unroll
            for (int i = 0; i < 8; ++i)
                op[i] = make_float4(o[4*i], o[4*i+1], o[4*i+2], o[4*i+3]);
        } else if (mtx == 1) {
            uint32_t dw[16];
            #pragma unroll
            for (int k = 0; k < 16; ++k) dw[k] = cvt_pk_bf16(o[2*k], o[2*k+1]);
            uint4* kp = reinterpret_cast<uint4*>((char*)Kb + (size_t)row * 64);
            #pragma unroll
            for (int q = 0; q < 4; ++q)
                kp[q] = make_uint4(dw[4*q], dw[4*q+1], dw[4*q+2], dw[4*q+3]);
        } else {
            #pragma unroll
            for (int k = 0; k < 16; ++k)
                *reinterpret_cast<uint32_t*>(&vs[tid][2*k]) = cvt_pk_bf16(o[2*k], o[2*k+1]);
        }
    }
    __syncthreads();
    // transpose-out: Vt[b][d][4096] bf16; this block covers s-range [seg*256, +255] of batch b
    const int b = blockIdx.x >> 4, seg = blockIdx.x & 15;
    const int d = tid >> 3, part = tid & 7;
    uint32_t dw[16];
    #pragma unroll
    for (int k = 0; k < 16; ++k) {
        const uint32_t lo = vs[part*32 + 2*k][d];
        const uint32_t hi = vs[part*32 + 2*k + 1][d];
        dw[k] = lo | (hi << 16);
    }
    uint16_t* dst = Vt + (size_t)b * (CCH * TTN) + (size_t)d * TTN + seg * 256 + part * 32;
    uint4* dp = reinterpret_cast<uint4*>(dst);
    #pragma unroll
    for (int q = 0; q < 4; ++q)
        dp[q] = make_uint4(dw[4*q], dw[4*q+1], dw[4*q+2], dw[4*q+3]);
}

// ---------------- MFMA flash attention ----------------
// Block = (batch b=j&7, 32-row q-tile, LPT order). 8 waves: thalf=w&1 (16 t-rows),
// sg=w>>1 (32-s slice per 128-s window). Per wave-window:
//   S^T = mfma(K-frag, Q-frag) x2  -> lane holds 8 scores, t = lane&15 LOCAL
//   online softmax (m,l per t; 2x shfl_xor reduce over the 4 g-groups)
//   dropout via precomputed MW word; P -> bf16 (cvt_pk) -> 8-shfl k-redistribution
//   O^T accum = mfma(Vt-frag, P-frag, acc) x2 -> t stays lane-local for rescale/divide
template<int PRE>
__global__ __launch_bounds__(512, 4) void attn_mfma(const float* __restrict__ Qf,
                                                    const uint16_t* __restrict__ Kb,
                                                    const uint16_t* __restrict__ Vt,
                                                    const uint32_t* __restrict__ MW,
                                                    float* __restrict__ out) {
    __shared__ __align__(16) char smem[33792];  // dbuf x (K 8192B + Vt 32x272B)

    const int j = blockIdx.x;
    const int b = j & 7;
    const int tile = 127 - (j >> 3);
    const int w = threadIdx.x >> 6;
    const int lane = threadIdx.x & 63;
    const int tl = lane & 15;
    const int g = lane >> 4;
    const int thalf = w & 1;
    const int sg = w >> 1;
    const int slb = sg * 32;
    const int t0 = tile * 32;
    const int t_g = t0 + thalf * 16 + tl;

    // Q fragment (B-operand: col=t=lane&15, k=d=8g+j), bf16, loaded once
    const float* qrow = Qf + ((size_t)b * TTN + t_g) * CCH + g * 8;
    const float4 qa = *reinterpret_cast<const float4*>(qrow);
    const float4 qb = *reinterpret_cast<const float4*>(qrow + 4);
    B8 qf;
    qf.u[0] = cvt_pk_bf16(qa.x, qa.y); qf.u[1] = cvt_pk_bf16(qa.z, qa.w);
    qf.u[2] = cvt_pk_bf16(qb.x, qb.y); qf.u[3] = cvt_pk_bf16(qb.z, qb.w);

    f32x4 acc0 = {0.f,0.f,0.f,0.f}, acc1 = {0.f,0.f,0.f,0.f};
    float m = -1e30f, l = 0.f;

    const char* Kbb = (const char*)Kb + (size_t)b * TTN * 64;         // bf16 rows, 64B
    const char* Vbb = (const char*)Vt + (size_t)b * CCH * TTN * 2;    // bf16, [32][4096]
    const uint32_t idxb = ((uint32_t)b << 24) | ((uint32_t)t_g << 12);

    const int nwin = (32 * tile + 159) >> 7;

    uint4 sgK, sgV; uint32_t mw_cur = 0u, mw_nxt = 0u;
    const int krow_st = threadIdx.x >> 2, koff_st = (threadIdx.x & 3) * 16;
    const int vrow_st = threadIdx.x >> 4, voff_st = (threadIdx.x & 15) * 16;

#define ISSUE_KV(S0)                                                           \
    {                                                                          \
        sgK = *reinterpret_cast<const uint4*>(Kbb + (size_t)((S0) + krow_st) * 64 + koff_st); \
        sgV = *reinterpret_cast<const uint4*>(Vbb + (size_t)vrow_st * 8192 + (size_t)(S0) * 2 + voff_st); \
        if (PRE) mw_nxt = MW[((uint32_t)b << 19) | ((uint32_t)t_g << 7) | (uint32_t)(((S0) >> 5) + sg)]; \
    }
#define WRITE_KV(D)                                                            \
    {                                                                          \
        char* base = smem + (D) * 16896;                                       \
        *reinterpret_cast<uint4*>(base + krow_st * 64 + koff_st) = sgK;        \
        *reinterpret_cast<uint4*>(base + 8192 + vrow_st * 272 + voff_st) = sgV; \
    }

#define ATT_WINDOW(D, S0, TAIL)                                                \
    {                                                                          \
        const char* kb = smem + (D) * 16896;                                   \
        const char* vb = kb + 8192;                                            \
        B8 ka, kc, va, vc, pf;                                                 \
        ka.q = *reinterpret_cast<const uint4*>(kb + (slb + tl) * 64 + g * 16); \
        kc.q = *reinterpret_cast<const uint4*>(kb + (slb + 16 + tl) * 64 + g * 16); \
        va.q = *reinterpret_cast<const uint4*>(vb + tl * 272 + (slb + g * 8) * 2); \
        vc.q = *reinterpret_cast<const uint4*>(vb + (16 + tl) * 272 + (slb + g * 8) * 2); \
        const f32x4 zz = {0.f,0.f,0.f,0.f};                                    \
        f32x4 d0 = __builtin_amdgcn_mfma_f32_16x16x32_bf16(ka.v, qf.v, zz, 0, 0, 0); \
        f32x4 d1 = __builtin_amdgcn_mfma_f32_16x16x32_bf16(kc.v, qf.v, zz, 0, 0, 0); \
        if (TAIL) {                                                            \
            const int sv = (S0) + slb + 4 * g;                                 \
            d0.x = (sv + 0  <= t_g) ? d0.x : -1e30f;                           \
            d0.y = (sv + 1  <= t_g) ? d0.y : -1e30f;                           \
            d0.z = (sv + 2  <= t_g) ? d0.z : -1e30f;                           \
            d0.w = (sv + 3  <= t_g) ? d0.w : -1e30f;                           \
            d1.x = (sv + 16 <= t_g) ? d1.x : -1e30f;                           \
            d1.y = (sv + 17 <= t_g) ? d1.y : -1e30f;                           \
            d1.z = (sv + 18 <= t_g) ? d1.z : -1e30f;                           \
            d1.w = (sv + 19 <= t_g) ? d1.w : -1e30f;                           \
        }                                                                      \
        float mx = fmaxf(fmaxf(fmaxf(d0.x, d0.y), fmaxf(d0.z, d0.w)),          \
                         fmaxf(fmaxf(d1.x, d1.y), fmaxf(d1.z, d1.w)));         \
        mx = fmaxf(mx, __shfl_xor(mx, 16));                                    \
        mx = fmaxf(mx, __shfl_xor(mx, 32));                                    \
        const bool up = mx > m + 8.0f;          /* deferred-max rescale */     \
        const float corr = up ? __expf(m - mx) : 1.0f;                         \
        m = up ? mx : m;                                                       \
        l *= corr; acc0 *= corr; acc1 *= corr;                                 \
        float p0 = __expf(d0.x - m), p1 = __expf(d0.y - m);                    \
        float p2 = __expf(d0.z - m), p3 = __expf(d0.w - m);                    \
        float p4 = __expf(d1.x - m), p5 = __expf(d1.y - m);                    \
        float p6 = __expf(d1.z - m), p7 = __expf(d1.w - m);                    \
        if (TAIL) {                                                            \
            const float alive = ((S0) + slb <= t_g) ? 1.0f : 0.0f;             \
            p0 *= alive; p1 *= alive; p2 *= alive; p3 *= alive;                \
            p4 *= alive; p5 *= alive; p6 *= alive; p7 *= alive;                \
        }                                                                      \
        float ls = ((p0 + p1) + (p2 + p3)) + ((p4 + p5) + (p6 + p7));          \
        ls += __shfl_xor(ls, 16);                                              \
        ls += __shfl_xor(ls, 32);                                              \
        l += ls;                                                               \
        uint32_t mwv;                                                          \
        if (PRE) mwv = mw_cur >> (4 * g);                                      \
        else {                                                                 \
            const uint32_t ib = idxb | (uint32_t)((S0) + slb + 4 * g);         \
            mwv  = (mask_bits(ib + 0)  < KEEP_LT9) ? 1u       : 0u;            \
            mwv |= (mask_bits(ib + 1)  < KEEP_LT9) ? (1u<<1)  : 0u;            \
            mwv |= (mask_bits(ib + 2)  < KEEP_LT9) ? (1u<<2)  : 0u;            \
            mwv |= (mask_bits(ib + 3)  < KEEP_LT9) ? (1u<<3)  : 0u;            \
            mwv |= (mask_bits(ib + 16) < KEEP_LT9) ? (1u<<16) : 0u;            \
            mwv |= (mask_bits(ib + 17) < KEEP_LT9) ? (1u<<17) : 0u;            \
            mwv |= (mask_bits(ib + 18) < KEEP_LT9) ? (1u<<18) : 0u;            \
            mwv |= (mask_bits(ib + 19) < KEEP_LT9) ? (1u<<19) : 0u;            \
        }                                                                      \
        const float q0 = (mwv & 1u)        ? p0 : 0.f;                         \
        const float q1 = (mwv & (1u<<1))   ? p1 : 0.f;                         \
        const float q2 = (mwv & (1u<<2))   ? p2 : 0.f;                         \
        const float q3 = (mwv & (1u<<3))   ? p3 : 0.f;                         \
        const float q4 = (mwv & (1u<<16))  ? p4 : 0.f;                         \
        const float q5 = (mwv & (1u<<17))  ? p5 : 0.f;                         \
        const float q6 = (mwv & (1u<<18))  ? p6 : 0.f;                         \
        const float q7 = (mwv & (1u<<19))  ? p7 : 0.f;                         \
        const uint32_t k00 = cvt_pk_bf16(q0, q1), k01 = cvt_pk_bf16(q2, q3);   \
        const uint32_t k10 = cvt_pk_bf16(q4, q5), k11 = cvt_pk_bf16(q6, q7);   \
        const int srcA = 16 * ((g & 1) * 2) + tl;                              \
        const int srcB = srcA + 16;                                            \
        const uint32_t a0 = (uint32_t)__shfl((int)k00, srcA);                  \
        const uint32_t b0 = (uint32_t)__shfl((int)k10, srcA);                  \
        const uint32_t a1 = (uint32_t)__shfl((int)k01, srcA);                  \
        const uint32_t b1 = (uint32_t)__shfl((int)k11, srcA);                  \
        const uint32_t a2 = (uint32_t)__shfl((int)k00, srcB);                  \
        const uint32_t b2 = (uint32_t)__shfl((int)k10, srcB);                  \
        const uint32_t a3 = (uint32_t)__shfl((int)k01, srcB);                  \
        const uint32_t b3 = (uint32_t)__shfl((int)k11, srcB);                  \
        const bool hi = (g >= 2);                                              \
        pf.u[0] = hi ? b0 : a0; pf.u[1] = hi ? b1 : a1;                        \
        pf.u[2] = hi ? b2 : a2; pf.u[3] = hi ? b3 : a3;                        \
        acc0 = __builtin_amdgcn_mfma_f32_16x16x32_bf16(va.v, pf.v, acc0, 0, 0, 0); \
        acc1 = __builtin_amdgcn_mfma_f32_16x16x32_bf16(vc.v, pf.v, acc1, 0, 0, 0); \
    }

    ISSUE_KV(0)
    WRITE_KV(0)
    __syncthreads();
    mw_cur = mw_nxt;

    int buf = 0;
    for (int win = 0; win < nwin - 1; ++win) {      // bulk: fully valid
        const int s0 = win << 7;
        ISSUE_KV(s0 + WIN)
        ATT_WINDOW(buf, s0, 0)
        WRITE_KV(buf ^ 1)
        __syncthreads();
        buf ^= 1;
        mw_cur = mw_nxt;
    }
    {                                                // tail: causal
        const int s0 = (nwin - 1) << 7;
        if (s0 + slb <= t0 + thalf * 16 + 15) ATT_WINDOW(buf, s0, 1)
        __syncthreads();
    }
#undef ATT_WINDOW
#undef ISSUE_KV
#undef WRITE_KV

    // ---- merge the 4 s-groups per t-half (aliases staging LDS) ----
    // slot: acc[16 t][36 c] f32 (2304B) + ml[16][2] (128B) = 2432B; 4 slots
#define SLOT(TH, S) reinterpret_cast<float*>(smem + ((TH) * 2 + (S)) * 2432)
#define PUBLISH(SB)                                                            \
    {                                                                          \
        float* sb = (SB);                                                      \
        *reinterpret_cast<float4*>(sb + tl * 36 + 4 * g)      = make_float4(acc0.x, acc0.y, acc0.z, acc0.w); \
        *reinterpret_cast<float4*>(sb + tl * 36 + 16 + 4 * g) = make_float4(acc1.x, acc1.y, acc1.z, acc1.w); \
        if (g == 0) { sb[576 + 2 * tl] = m; sb[577 + 2 * tl] = l; }            \
    }
#define CONSUME(SB)                                                            \
    {                                                                          \
        const float* sb = (SB);                                                \
        const float m2 = sb[576 + 2 * tl], l2 = sb[577 + 2 * tl];              \
        const float4 x0 = *reinterpret_cast<const float4*>(sb + tl * 36 + 4 * g); \
        const float4 x1 = *reinterpret_cast<const float4*>(sb + tl * 36 + 16 + 4 * g); \
        const float mn = fmaxf(m, m2);                                         \
        const float ca = __expf(m - mn), cb = __expf(m2 - mn);                 \
        l = l * ca + l2 * cb;                                                  \
        acc0.x = acc0.x * ca + x0.x * cb; acc0.y = acc0.y * ca + x0.y * cb;    \
        acc0.z = acc0.z * ca + x0.z * cb; acc0.w = acc0.w * ca + x0.w * cb;    \
        acc1.x = acc1.x * ca + x1.x * cb; acc1.y = acc1.y * ca + x1.y * cb;    \
        acc1.z = acc1.z * ca + x1.z * cb; acc1.w = acc1.w * ca + x1.w * cb;    \
        m = mn;                                                                \
    }
    if (sg >= 2) PUBLISH(SLOT(thalf, sg - 2))
    __syncthreads();
    if (sg < 2) CONSUME(SLOT(thalf, sg))
    __syncthreads();
    if (sg == 1) PUBLISH(SLOT(thalf, 0))
    __syncthreads();
    if (sg == 0) {
        CONSUME(SLOT(thalf, 0))
        const float inv = 1.0f / (0.8f * l);            // l,t lane-local
        float* orow = out + ((size_t)b * TTN + t_g) * CCH;
        *reinterpret_cast<float4*>(orow + 4 * g) =
            make_float4(acc0.x * inv, acc0.y * inv, acc0.z * inv, acc0.w * inv);
        *reinterpret_cast<float4*>(orow + 16 + 4 * g) =
            make_float4(acc1.x * inv, acc1.y * inv, acc1.z * inv, acc1.w * inv);
    }
#undef SLOT
#undef PUBLISH
#undef CONSUME
}

extern "C" void kernel_launch(void* const* d_in, const int* in_sizes, int n_in,
                              void* d_out, int out_size, void* d_ws, size_t ws_size,
                              hipStream_t stream) {
    const float* x  = (const float*)d_in[0];
    const float* Wq = (const float*)d_in[1];
    const float* Wk = (const float*)d_in[2];
    const float* Wv = (const float*)d_in[3];
    float* outp = (float*)d_out;

    // workspace: Qf fp32 4MiB | Kb bf16 2MiB | Vt bf16 2MiB | MW bits 16MiB
    float*    Qf = (float*)d_ws;
    uint16_t* Kb = (uint16_t*)((char*)d_ws + 4194304);
    uint16_t* Vt = (uint16_t*)((char*)d_ws + 6291456);
    uint32_t* MW = (uint32_t*)((char*)d_ws + 8388608);
    const size_t need = 8388608 + 16777216;

    proj_qkv<<<(BB * TTN) / 256, 256, 0, stream>>>(x, Wq, Wk, Wv, Qf, Kb, Vt);
    if (ws_size >= need) {
        mask_pass<<<2048, 256, 0, stream>>>(MW);
        attn_mfma<1><<<1024, 512, 0, stream>>>(Qf, Kb, Vt, MW, outp);
    } else {
        attn_mfma<0><<<1024, 512, 0, stream>>>(Qf, Kb, Vt, nullptr, outp);
    }
}

// Round 10
// 175.259 us; speedup vs baseline: 3.2243x; 1.3631x over previous
//
#include <hip/hip_runtime.h>
#include <stdint.h>

#define BB 8
#define TTN 4096
#define CCH 32
#define WIN 128
#define KEEP_LT9 3435974144u   // keep iff bits < this (uniform < 0.8f)

typedef __attribute__((ext_vector_type(8))) short bf16x8;
typedef __attribute__((ext_vector_type(4))) float f32x4;

union B8 { uint32_t u[4]; uint4 q; bf16x8 v; };

__device__ __forceinline__ uint32_t cvt_pk_bf16(float lo, float hi) {
    uint32_t d;
    asm("v_cvt_pk_bf16_f32 %0, %1, %2" : "=v"(d) : "v"(lo), "v"(hi));
    return d;
}

// rotl via funnel-shift: alignbit(x,x,32-r) == rotr(x,32-r) == rotl(x,r), 1 VALU inst
__device__ __forceinline__ uint32_t rotl32(uint32_t x, int r) {
    return __builtin_amdgcn_alignbit(x, x, 32 - r);
}

// threefry2x32, 20 rounds, key (0, 42) == jax.random.key(42)
__device__ __forceinline__ void threefry2x32_k042(uint32_t x0, uint32_t x1,
                                                  uint32_t& o0, uint32_t& o1) {
    const uint32_t k0 = 0u, k1 = 42u;
    const uint32_t k2 = 0u ^ 42u ^ 0x1BD11BDAu;
    x0 += k0; x1 += k1;
#define TFR(r) { x0 += x1; x1 = rotl32(x1, (r)); x1 ^= x0; }
    TFR(13) TFR(15) TFR(26) TFR(6)
    x0 += k1; x1 += k2 + 1u;
    TFR(17) TFR(29) TFR(16) TFR(24)
    x0 += k2; x1 += k0 + 2u;
    TFR(13) TFR(15) TFR(26) TFR(6)
    x0 += k0; x1 += k1 + 3u;
    TFR(17) TFR(29) TFR(16) TFR(24)
    x0 += k1; x1 += k2 + 4u;
    TFR(13) TFR(15) TFR(26) TFR(6)
    x0 += k2; x1 += k0 + 5u;
#undef TFR
    o0 = x0; o1 = x1;
}

// partitionable threefry draw: bits(i) = o0^o1 of threefry(key42, (0, i))
__device__ __forceinline__ uint32_t mask_bits(uint32_t idx) {
    uint32_t o0, o1; threefry2x32_k042(0u, idx, o0, o1); return o0 ^ o1;
}

// ---------------- projections: Q fp32 (scaled), K bf16 row-major, V bf16 TRANSPOSED ----------------
__global__ __launch_bounds__(256) void proj_qkv(const float* __restrict__ x,
                                                const float* __restrict__ Wq,
                                                const float* __restrict__ Wk,
                                                const float* __restrict__ Wv,
                                                float* __restrict__ Qf,
                                                uint16_t* __restrict__ Kb,
                                                uint16_t* __restrict__ Vt) {
    __shared__ float sW[3][CCH * CCH];
    __shared__ uint16_t vs[256][34];            // v bf16, padded row (bank spread)
    const int tid = threadIdx.x;
    for (int i = tid; i < CCH * CCH; i += 256) {
        sW[0][i] = Wq[i]; sW[1][i] = Wk[i]; sW[2][i] = Wv[i];
    }
    __syncthreads();
    const int row = blockIdx.x * 256 + tid;     // b*T + t
    const float4* xp = reinterpret_cast<const float4*>(x + (size_t)row * CCH);
    float xr[CCH];
    #pragma unroll
    for (int i = 0; i < 8; ++i) {
        float4 t4 = xp[i];
        xr[4*i] = t4.x; xr[4*i+1] = t4.y; xr[4*i+2] = t4.z; xr[4*i+3] = t4.w;
    }
    const float scale = 0.17677669529663687f;   // 1/sqrt(32)
    #pragma unroll
    for (int mtx = 0; mtx < 3; ++mtx) {
        float o[CCH];
        #pragma unroll
        for (int d = 0; d < CCH; ++d) {
            float s0 = 0.f, s1 = 0.f, s2 = 0.f, s3 = 0.f;
            #pragma unroll
            for (int c = 0; c < CCH; c += 4) {
                s0 += xr[c]   * sW[mtx][d*CCH + c];
                s1 += xr[c+1] * sW[mtx][d*CCH + c+1];
                s2 += xr[c+2] * sW[mtx][d*CCH + c+2];
                s3 += xr[c+3] * sW[mtx][d*CCH + c+3];
            }
            o[d] = (s0 + s1) + (s2 + s3);
            if (mtx == 0) o[d] *= scale;
        }
        if (mtx == 0) {
            float4* op = reinterpret_cast<float4*>(Qf + (size_t)row * CCH);
            #pragma unroll
            for (int i = 0; i < 8; ++i)
                op[i] = make_float4(o[4*i], o[4*i+1], o[4*i+2], o[4*i+3]);
        } else if (mtx == 1) {
            uint32_t dw[16];
            #pragma unroll
            for (int k = 0; k < 16; ++k) dw[k] = cvt_pk_bf16(o[2*k], o[2*k+1]);
            uint4* kp = reinterpret_cast<uint4*>((char*)Kb + (size_t)row * 64);
            #pragma unroll
            for (int q = 0; q < 4; ++q)
                kp[q] = make_uint4(dw[4*q], dw[4*q+1], dw[4*q+2], dw[4*q+3]);
        } else {
            #pragma unroll
            for (int k = 0; k < 16; ++k)
                *reinterpret_cast<uint32_t*>(&vs[tid][2*k]) = cvt_pk_bf16(o[2*k], o[2*k+1]);
        }
    }
    __syncthreads();
    // transpose-out: Vt[b][d][4096] bf16; this block covers s-range [seg*256, +255] of batch b
    const int b = blockIdx.x >> 4, seg = blockIdx.x & 15;
    const int d = tid >> 3, part = tid & 7;
    uint32_t dw[16];
    #pragma unroll
    for (int k = 0; k < 16; ++k) {
        const uint32_t lo = vs[part*32 + 2*k][d];
        const uint32_t hi = vs[part*32 + 2*k + 1][d];
        dw[k] = lo | (hi << 16);
    }
    uint16_t* dst = Vt + (size_t)b * (CCH * TTN) + (size_t)d * TTN + seg * 256 + part * 32;
    uint4* dp = reinterpret_cast<uint4*>(dst);
    #pragma unroll
    for (int q = 0; q < 4; ++q)
        dp[q] = make_uint4(dw[4*q], dw[4*q+1], dw[4*q+2], dw[4*q+3]);
}

// ---------------- MFMA flash attention with FUSED threefry dropout ----------------
// Block = (batch b=j&7, 32-row q-tile, LPT order). 8 waves: thalf=w&1 (16 t-rows),
// sg=w>>1 (32-s slice per 128-s window). Per wave-window:
//   S^T = mfma(K-frag, Q-frag) x2  -> lane holds 8 scores, t = lane&15 LOCAL
//   online softmax (m,l per t; 2x shfl_xor reduce over the 4 g-groups)
//   dropout: 8 inline threefrys (independent chains, alignbit rotl) select p->0
//   P -> bf16 (cvt_pk) -> 8-shfl k-redistribution
//   O^T accum = mfma(Vt-frag, P-frag, acc) x2 -> t stays lane-local to the end
__global__ __launch_bounds__(512, 4) void attn_mfma(const float* __restrict__ Qf,
                                                    const uint16_t* __restrict__ Kb,
                                                    const uint16_t* __restrict__ Vt,
                                                    float* __restrict__ out) {
    __shared__ __align__(16) char smem[33792];  // dbuf x (K 8192B + Vt 32x272B)

    const int j = blockIdx.x;
    const int b = j & 7;
    const int tile = 127 - (j >> 3);
    const int w = threadIdx.x >> 6;
    const int lane = threadIdx.x & 63;
    const int tl = lane & 15;
    const int g = lane >> 4;
    const int thalf = w & 1;
    const int sg = w >> 1;
    const int slb = sg * 32;
    const int t0 = tile * 32;
    const int t_g = t0 + thalf * 16 + tl;

    // Q fragment (B-operand: col=t=lane&15, k=d=8g+j), bf16, loaded once
    const float* qrow = Qf + ((size_t)b * TTN + t_g) * CCH + g * 8;
    const float4 qa = *reinterpret_cast<const float4*>(qrow);
    const float4 qb = *reinterpret_cast<const float4*>(qrow + 4);
    B8 qf;
    qf.u[0] = cvt_pk_bf16(qa.x, qa.y); qf.u[1] = cvt_pk_bf16(qa.z, qa.w);
    qf.u[2] = cvt_pk_bf16(qb.x, qb.y); qf.u[3] = cvt_pk_bf16(qb.z, qb.w);

    f32x4 acc0 = {0.f,0.f,0.f,0.f}, acc1 = {0.f,0.f,0.f,0.f};
    float m = -1e30f, l = 0.f;

    const char* Kbb = (const char*)Kb + (size_t)b * TTN * 64;         // bf16 rows, 64B
    const char* Vbb = (const char*)Vt + (size_t)b * CCH * TTN * 2;    // bf16, [32][4096]
    const uint32_t idxb = ((uint32_t)b << 24) | ((uint32_t)t_g << 12);

    const int nwin = (32 * tile + 159) >> 7;

    uint4 sgK, sgV;
    const int krow_st = threadIdx.x >> 2, koff_st = (threadIdx.x & 3) * 16;
    const int vrow_st = threadIdx.x >> 4, voff_st = (threadIdx.x & 15) * 16;

#define ISSUE_KV(S0)                                                           \
    {                                                                          \
        sgK = *reinterpret_cast<const uint4*>(Kbb + (size_t)((S0) + krow_st) * 64 + koff_st); \
        sgV = *reinterpret_cast<const uint4*>(Vbb + (size_t)vrow_st * 8192 + (size_t)(S0) * 2 + voff_st); \
    }
#define WRITE_KV(D)                                                            \
    {                                                                          \
        char* base = smem + (D) * 16896;                                       \
        *reinterpret_cast<uint4*>(base + krow_st * 64 + koff_st) = sgK;        \
        *reinterpret_cast<uint4*>(base + 8192 + vrow_st * 272 + voff_st) = sgV; \
    }

#define ATT_WINDOW(D, S0, TAIL)                                                \
    {                                                                          \
        const char* kb = smem + (D) * 16896;                                   \
        const char* vb = kb + 8192;                                            \
        B8 ka, kc, va, vc, pf;                                                 \
        ka.q = *reinterpret_cast<const uint4*>(kb + (slb + tl) * 64 + g * 16); \
        kc.q = *reinterpret_cast<const uint4*>(kb + (slb + 16 + tl) * 64 + g * 16); \
        va.q = *reinterpret_cast<const uint4*>(vb + tl * 272 + (slb + g * 8) * 2); \
        vc.q = *reinterpret_cast<const uint4*>(vb + (16 + tl) * 272 + (slb + g * 8) * 2); \
        const f32x4 zz = {0.f,0.f,0.f,0.f};                                    \
        f32x4 d0 = __builtin_amdgcn_mfma_f32_16x16x32_bf16(ka.v, qf.v, zz, 0, 0, 0); \
        f32x4 d1 = __builtin_amdgcn_mfma_f32_16x16x32_bf16(kc.v, qf.v, zz, 0, 0, 0); \
        if (TAIL) {                                                            \
            const int sv = (S0) + slb + 4 * g;                                 \
            d0.x = (sv + 0  <= t_g) ? d0.x : -1e30f;                           \
            d0.y = (sv + 1  <= t_g) ? d0.y : -1e30f;                           \
            d0.z = (sv + 2  <= t_g) ? d0.z : -1e30f;                           \
            d0.w = (sv + 3  <= t_g) ? d0.w : -1e30f;                           \
            d1.x = (sv + 16 <= t_g) ? d1.x : -1e30f;                           \
            d1.y = (sv + 17 <= t_g) ? d1.y : -1e30f;                           \
            d1.z = (sv + 18 <= t_g) ? d1.z : -1e30f;                           \
            d1.w = (sv + 19 <= t_g) ? d1.w : -1e30f;                           \
        }                                                                      \
        float mx = fmaxf(fmaxf(fmaxf(d0.x, d0.y), fmaxf(d0.z, d0.w)),          \
                         fmaxf(fmaxf(d1.x, d1.y), fmaxf(d1.z, d1.w)));         \
        mx = fmaxf(mx, __shfl_xor(mx, 16));                                    \
        mx = fmaxf(mx, __shfl_xor(mx, 32));                                    \
        const bool up = mx > m + 8.0f;          /* deferred-max rescale */     \
        const float corr = up ? __expf(m - mx) : 1.0f;                         \
        m = up ? mx : m;                                                       \
        l *= corr; acc0 *= corr; acc1 *= corr;                                 \
        float p0 = __expf(d0.x - m), p1 = __expf(d0.y - m);                    \
        float p2 = __expf(d0.z - m), p3 = __expf(d0.w - m);                    \
        float p4 = __expf(d1.x - m), p5 = __expf(d1.y - m);                    \
        float p6 = __expf(d1.z - m), p7 = __expf(d1.w - m);                    \
        if (TAIL) {                                                            \
            const float alive = ((S0) + slb <= t_g) ? 1.0f : 0.0f;             \
            p0 *= alive; p1 *= alive; p2 *= alive; p3 *= alive;                \
            p4 *= alive; p5 *= alive; p6 *= alive; p7 *= alive;                \
        }                                                                      \
        float ls = ((p0 + p1) + (p2 + p3)) + ((p4 + p5) + (p6 + p7));          \
        ls += __shfl_xor(ls, 16);                                              \
        ls += __shfl_xor(ls, 32);                                              \
        l += ls;                                                               \
        /* fused dropout: 8 independent threefry chains, select p -> 0 */      \
        const uint32_t ib = idxb | (uint32_t)((S0) + slb + 4 * g);             \
        const float q0 = (mask_bits(ib + 0)  < KEEP_LT9) ? p0 : 0.f;           \
        const float q1 = (mask_bits(ib + 1)  < KEEP_LT9) ? p1 : 0.f;           \
        const float q2 = (mask_bits(ib + 2)  < KEEP_LT9) ? p2 : 0.f;           \
        const float q3 = (mask_bits(ib + 3)  < KEEP_LT9) ? p3 : 0.f;           \
        const float q4 = (mask_bits(ib + 16) < KEEP_LT9) ? p4 : 0.f;           \
        const float q5 = (mask_bits(ib + 17) < KEEP_LT9) ? p5 : 0.f;           \
        const float q6 = (mask_bits(ib + 18) < KEEP_LT9) ? p6 : 0.f;           \
        const float q7 = (mask_bits(ib + 19) < KEEP_LT9) ? p7 : 0.f;           \
        const uint32_t k00 = cvt_pk_bf16(q0, q1), k01 = cvt_pk_bf16(q2, q3);   \
        const uint32_t k10 = cvt_pk_bf16(q4, q5), k11 = cvt_pk_bf16(q6, q7);   \
        const int srcA = 16 * ((g & 1) * 2) + tl;                              \
        const int srcB = srcA + 16;                                            \
        const uint32_t a0 = (uint32_t)__shfl((int)k00, srcA);                  \
        const uint32_t b0 = (uint32_t)__shfl((int)k10, srcA);                  \
        const uint32_t a1 = (uint32_t)__shfl((int)k01, srcA);                  \
        const uint32_t b1 = (uint32_t)__shfl((int)k11, srcA);                  \
        const uint32_t a2 = (uint32_t)__shfl((int)k00, srcB);                  \
        const uint32_t b2 = (uint32_t)__shfl((int)k10, srcB);                  \
        const uint32_t a3 = (uint32_t)__shfl((int)k01, srcB);                  \
        const uint32_t b3 = (uint32_t)__shfl((int)k11, srcB);                  \
        const bool hi = (g >= 2);                                              \
        pf.u[0] = hi ? b0 : a0; pf.u[1] = hi ? b1 : a1;                        \
        pf.u[2] = hi ? b2 : a2; pf.u[3] = hi ? b3 : a3;                        \
        acc0 = __builtin_amdgcn_mfma_f32_16x16x32_bf16(va.v, pf.v, acc0, 0, 0, 0); \
        acc1 = __builtin_amdgcn_mfma_f32_16x16x32_bf16(vc.v, pf.v, acc1, 0, 0, 0); \
    }

    ISSUE_KV(0)
    WRITE_KV(0)
    __syncthreads();

    int buf = 0;
    for (int win = 0; win < nwin - 1; ++win) {      // bulk: fully valid
        const int s0 = win << 7;
        ISSUE_KV(s0 + WIN)
        ATT_WINDOW(buf, s0, 0)
        WRITE_KV(buf ^ 1)
        __syncthreads();
        buf ^= 1;
    }
    {                                                // tail: causal
        const int s0 = (nwin - 1) << 7;
        if (s0 + slb <= t0 + thalf * 16 + 15) ATT_WINDOW(buf, s0, 1)
        __syncthreads();
    }
#undef ATT_WINDOW
#undef ISSUE_KV
#undef WRITE_KV

    // ---- merge the 4 s-groups per t-half (aliases staging LDS) ----
    // slot: acc[16 t][36 c] f32 (2304B) + ml[16][2] (128B) = 2432B; 4 slots
#define SLOT(TH, S) reinterpret_cast<float*>(smem + ((TH) * 2 + (S)) * 2432)
#define PUBLISH(SB)                                                            \
    {                                                                          \
        float* sb = (SB);                                                      \
        *reinterpret_cast<float4*>(sb + tl * 36 + 4 * g)      = make_float4(acc0.x, acc0.y, acc0.z, acc0.w); \
        *reinterpret_cast<float4*>(sb + tl * 36 + 16 + 4 * g) = make_float4(acc1.x, acc1.y, acc1.z, acc1.w); \
        if (g == 0) { sb[576 + 2 * tl] = m; sb[577 + 2 * tl] = l; }            \
    }
#define CONSUME(SB)                                                            \
    {                                                                          \
        const float* sb = (SB);                                                \
        const float m2 = sb[576 + 2 * tl], l2 = sb[577 + 2 * tl];              \
        const float4 x0 = *reinterpret_cast<const float4*>(sb + tl * 36 + 4 * g); \
        const float4 x1 = *reinterpret_cast<const float4*>(sb + tl * 36 + 16 + 4 * g); \
        const float mn = fmaxf(m, m2);                                         \
        const float ca = __expf(m - mn), cb = __expf(m2 - mn);                 \
        l = l * ca + l2 * cb;                                                  \
        acc0.x = acc0.x * ca + x0.x * cb; acc0.y = acc0.y * ca + x0.y * cb;    \
        acc0.z = acc0.z * ca + x0.z * cb; acc0.w = acc0.w * ca + x0.w * cb;    \
        acc1.x = acc1.x * ca + x1.x * cb; acc1.y = acc1.y * ca + x1.y * cb;    \
        acc1.z = acc1.z * ca + x1.z * cb; acc1.w = acc1.w * ca + x1.w * cb;    \
        m = mn;                                                                \
    }
    if (sg >= 2) PUBLISH(SLOT(thalf, sg - 2))
    __syncthreads();
    if (sg < 2) CONSUME(SLOT(thalf, sg))
    __syncthreads();
    if (sg == 1) PUBLISH(SLOT(thalf, 0))
    __syncthreads();
    if (sg == 0) {
        CONSUME(SLOT(thalf, 0))
        const float inv = 1.0f / (0.8f * l);            // l,t lane-local
        float* orow = out + ((size_t)b * TTN + t_g) * CCH;
        *reinterpret_cast<float4*>(orow + 4 * g) =
            make_float4(acc0.x * inv, acc0.y * inv, acc0.z * inv, acc0.w * inv);
        *reinterpret_cast<float4*>(orow + 16 + 4 * g) =
            make_float4(acc1.x * inv, acc1.y * inv, acc1.z * inv, acc1.w * inv);
    }
#undef SLOT
#undef PUBLISH
#undef CONSUME
}

extern "C" void kernel_launch(void* const* d_in, const int* in_sizes, int n_in,
                              void* d_out, int out_size, void* d_ws, size_t ws_size,
                              hipStream_t stream) {
    const float* x  = (const float*)d_in[0];
    const float* Wq = (const float*)d_in[1];
    const float* Wk = (const float*)d_in[2];
    const float* Wv = (const float*)d_in[3];
    float* outp = (float*)d_out;

    // workspace: Qf fp32 4MiB | Kb bf16 2MiB | Vt bf16 2MiB
    float*    Qf = (float*)d_ws;
    uint16_t* Kb = (uint16_t*)((char*)d_ws + 4194304);
    uint16_t* Vt = (uint16_t*)((char*)d_ws + 6291456);

    proj_qkv<<<(BB * TTN) / 256, 256, 0, stream>>>(x, Wq, Wk, Wv, Qf, Kb, Vt);
    attn_mfma<<<1024, 512, 0, stream>>>(Qf, Kb, Vt, outp);
}

// Round 11
// 168.233 us; speedup vs baseline: 3.3590x; 1.0418x over previous
//
#include <hip/hip_runtime.h>
#include <stdint.h>

#define BB 8
#define TTN 4096
#define CCH 32
#define WIN 128
#define KEEP_LT9 3435974144u   // keep iff bits < this (uniform < 0.8f)

typedef __attribute__((ext_vector_type(8))) short bf16x8;
typedef __attribute__((ext_vector_type(4))) float f32x4;

union B8 { uint32_t u[4]; uint4 q; bf16x8 v; };

__device__ __forceinline__ uint32_t cvt_pk_bf16(float lo, float hi) {
    uint32_t d;
    asm("v_cvt_pk_bf16_f32 %0, %1, %2" : "=v"(d) : "v"(lo), "v"(hi));
    return d;
}

// rotl via funnel-shift: 1 VALU inst
__device__ __forceinline__ uint32_t rotl32(uint32_t x, int r) {
    return __builtin_amdgcn_alignbit(x, x, 32 - r);
}

// threefry2x32 key(0,42), scalar (used by proj? no — kept for reference/tail use)
__device__ __forceinline__ uint32_t mask_bits(uint32_t idx) {
    uint32_t x0 = 0u, x1 = idx + 42u;
    const uint32_t K2 = 42u ^ 0x1BD11BDAu;
#define TFR(r) { x0 += x1; x1 = rotl32(x1, (r)); x1 ^= x0; }
    TFR(13) TFR(15) TFR(26) TFR(6)
    x0 += 42u; x1 += K2 + 1u;
    TFR(17) TFR(29) TFR(16) TFR(24)
    x0 += K2; x1 += 2u;
    TFR(13) TFR(15) TFR(26) TFR(6)
    x1 += 42u + 3u;
    TFR(17) TFR(29) TFR(16) TFR(24)
    x0 += 42u; x1 += K2 + 4u;
    TFR(13) TFR(15) TFR(26) TFR(6)
    x0 += K2; x1 += 5u;
#undef TFR
    return x0 ^ x1;
}

// 4 interleaved threefry2x32 chains (explicit ILP; key (0,42); out = o0^o1)
__device__ __forceinline__ void threefry4(uint32_t i0, uint32_t i1, uint32_t i2, uint32_t i3,
                                          uint32_t& o0, uint32_t& o1, uint32_t& o2, uint32_t& o3) {
    const uint32_t K2 = 42u ^ 0x1BD11BDAu;
    uint32_t a0 = 0u, a1 = 0u, a2 = 0u, a3 = 0u;
    uint32_t b0 = i0 + 42u, b1 = i1 + 42u, b2 = i2 + 42u, b3 = i3 + 42u;
#define R4(r)                                                                  \
    { a0 += b0; a1 += b1; a2 += b2; a3 += b3;                                  \
      b0 = rotl32(b0, (r)); b1 = rotl32(b1, (r));                              \
      b2 = rotl32(b2, (r)); b3 = rotl32(b3, (r));                              \
      b0 ^= a0; b1 ^= a1; b2 ^= a2; b3 ^= a3; }
#define INJ(da, db)                                                            \
    { a0 += (da); a1 += (da); a2 += (da); a3 += (da);                          \
      b0 += (db); b1 += (db); b2 += (db); b3 += (db); }
    R4(13) R4(15) R4(26) R4(6)
    INJ(42u, K2 + 1u)
    R4(17) R4(29) R4(16) R4(24)
    INJ(K2, 2u)
    R4(13) R4(15) R4(26) R4(6)
    INJ(0u, 42u + 3u)
    R4(17) R4(29) R4(16) R4(24)
    INJ(42u, K2 + 4u)
    R4(13) R4(15) R4(26) R4(6)
    INJ(K2, 5u)
#undef R4
#undef INJ
    o0 = a0 ^ b0; o1 = a1 ^ b1; o2 = a2 ^ b2; o3 = a3 ^ b3;
}

// ---------------- projections: Q fp32 (scaled), K bf16 row-major, V bf16 TRANSPOSED ----------------
__global__ __launch_bounds__(256) void proj_qkv(const float* __restrict__ x,
                                                const float* __restrict__ Wq,
                                                const float* __restrict__ Wk,
                                                const float* __restrict__ Wv,
                                                float* __restrict__ Qf,
                                                uint16_t* __restrict__ Kb,
                                                uint16_t* __restrict__ Vt) {
    __shared__ float sW[3][CCH * CCH];
    __shared__ uint16_t vs[256][34];            // v bf16, padded row (bank spread)
    const int tid = threadIdx.x;
    for (int i = tid; i < CCH * CCH; i += 256) {
        sW[0][i] = Wq[i]; sW[1][i] = Wk[i]; sW[2][i] = Wv[i];
    }
    __syncthreads();
    const int row = blockIdx.x * 256 + tid;     // b*T + t
    const float4* xp = reinterpret_cast<const float4*>(x + (size_t)row * CCH);
    float xr[CCH];
    #pragma unroll
    for (int i = 0; i < 8; ++i) {
        float4 t4 = xp[i];
        xr[4*i] = t4.x; xr[4*i+1] = t4.y; xr[4*i+2] = t4.z; xr[4*i+3] = t4.w;
    }
    const float scale = 0.17677669529663687f;   // 1/sqrt(32)
    #pragma unroll
    for (int mtx = 0; mtx < 3; ++mtx) {
        float o[CCH];
        #pragma unroll
        for (int d = 0; d < CCH; ++d) {
            float s0 = 0.f, s1 = 0.f, s2 = 0.f, s3 = 0.f;
            #pragma unroll
            for (int c = 0; c < CCH; c += 4) {
                s0 += xr[c]   * sW[mtx][d*CCH + c];
                s1 += xr[c+1] * sW[mtx][d*CCH + c+1];
                s2 += xr[c+2] * sW[mtx][d*CCH + c+2];
                s3 += xr[c+3] * sW[mtx][d*CCH + c+3];
            }
            o[d] = (s0 + s1) + (s2 + s3);
            if (mtx == 0) o[d] *= scale;
        }
        if (mtx == 0) {
            float4* op = reinterpret_cast<float4*>(Qf + (size_t)row * CCH);
            #pragma unroll
            for (int i = 0; i < 8; ++i)
                op[i] = make_float4(o[4*i], o[4*i+1], o[4*i+2], o[4*i+3]);
        } else if (mtx == 1) {
            uint32_t dw[16];
            #pragma unroll
            for (int k = 0; k < 16; ++k) dw[k] = cvt_pk_bf16(o[2*k], o[2*k+1]);
            uint4* kp = reinterpret_cast<uint4*>((char*)Kb + (size_t)row * 64);
            #pragma unroll
            for (int q = 0; q < 4; ++q)
                kp[q] = make_uint4(dw[4*q], dw[4*q+1], dw[4*q+2], dw[4*q+3]);
        } else {
            #pragma unroll
            for (int k = 0; k < 16; ++k)
                *reinterpret_cast<uint32_t*>(&vs[tid][2*k]) = cvt_pk_bf16(o[2*k], o[2*k+1]);
        }
    }
    __syncthreads();
    // transpose-out: Vt[b][d][4096] bf16; block covers s-range [seg*256, +255] of batch b
    const int b = blockIdx.x >> 4, seg = blockIdx.x & 15;
    const int d = tid >> 3, part = tid & 7;
    uint32_t dw[16];
    #pragma unroll
    for (int k = 0; k < 16; ++k) {
        const uint32_t lo = vs[part*32 + 2*k][d];
        const uint32_t hi = vs[part*32 + 2*k + 1][d];
        dw[k] = lo | (hi << 16);
    }
    uint16_t* dst = Vt + (size_t)b * (CCH * TTN) + (size_t)d * TTN + seg * 256 + part * 32;
    uint4* dp = reinterpret_cast<uint4*>(dst);
    #pragma unroll
    for (int q = 0; q < 4; ++q)
        dp[q] = make_uint4(dw[4*q], dw[4*q+1], dw[4*q+2], dw[4*q+3]);
}

// ---------------- MFMA flash attention, fused threefry, NO K/V staging ----------------
// Block = (batch b=j&7 -> XCD-local K/V in L2, 32-row q-tile via per-CU-balanced map).
// 8 waves: thalf=w&1 (16 t-rows), sg=w>>1 (32-s slice per 128-s window). Fragments
// loaded DIRECT from global (full-line coalesced); per window: issue loads ->
// threefry4 x2 (600 cy, hides L2 latency) -> mfma S^T -> online softmax ->
// dropout-select -> P->bf16 -> shfl redistribute -> mfma O^T. No barriers until
// the 3-stage LDS merge (9.7 KB).
__global__ __launch_bounds__(512, 4) void attn_mfma(const float* __restrict__ Qf,
                                                    const uint16_t* __restrict__ Kb,
                                                    const uint16_t* __restrict__ Vt,
                                                    float* __restrict__ out) {
    __shared__ __align__(16) char smem[9728];   // merge slots only

    const int j = blockIdx.x;
    const int b = j & 7;                        // XCD-local batch
    const int u = j >> 3;                       // 0..127
    // per-CU-constant map: CU gets u, u+32, u+64, u+96 -> tile sum 254 always
    const int tile = (u < 32) ? (127 - u) : (u < 64) ? (u - 32)
                   : (u < 96) ? (159 - u) : (u - 64);

    const int w = threadIdx.x >> 6;
    const int lane = threadIdx.x & 63;
    const int tl = lane & 15;
    const int g = lane >> 4;
    const int thalf = w & 1;
    const int sg = w >> 1;
    const int slb = sg * 32;
    const int t0 = tile * 32;
    const int t_g = t0 + thalf * 16 + tl;

    // Q fragment (B-operand: col=t=lane&15, k=d=8g+j), bf16, loaded once
    const float* qrow = Qf + ((size_t)b * TTN + t_g) * CCH + g * 8;
    const float4 qa = *reinterpret_cast<const float4*>(qrow);
    const float4 qb = *reinterpret_cast<const float4*>(qrow + 4);
    B8 qf;
    qf.u[0] = cvt_pk_bf16(qa.x, qa.y); qf.u[1] = cvt_pk_bf16(qa.z, qa.w);
    qf.u[2] = cvt_pk_bf16(qb.x, qb.y); qf.u[3] = cvt_pk_bf16(qb.z, qb.w);

    f32x4 acc0 = {0.f,0.f,0.f,0.f}, acc1 = {0.f,0.f,0.f,0.f};
    float m = -1e30f, l = 0.f;

    const char* Kbb = (const char*)Kb + (size_t)b * TTN * 64;         // bf16 rows, 64B
    const char* Vbb = (const char*)Vt + (size_t)b * CCH * TTN * 2;    // bf16 [32][4096]
    const uint32_t idxb = ((uint32_t)b << 24) | ((uint32_t)t_g << 12);

    const int nwin = (32 * tile + 159) >> 7;

#define ATT_WINDOW(S0, TAIL)                                                   \
    {                                                                          \
        const int srow = (S0) + slb;                                           \
        B8 ka, kc, va, vc, pf;                                                 \
        ka.q = *reinterpret_cast<const uint4*>(Kbb + (size_t)(srow + tl) * 64 + g * 16); \
        kc.q = *reinterpret_cast<const uint4*>(Kbb + (size_t)(srow + 16 + tl) * 64 + g * 16); \
        va.q = *reinterpret_cast<const uint4*>(Vbb + (size_t)tl * 8192 + (size_t)(srow + g * 8) * 2); \
        vc.q = *reinterpret_cast<const uint4*>(Vbb + (size_t)(16 + tl) * 8192 + (size_t)(srow + g * 8) * 2); \
        /* threefry first: ~600 cy of pure VALU hides the load latency */      \
        const uint32_t ib = idxb | (uint32_t)(srow + 4 * g);                   \
        uint32_t r0, r1, r2, r3, r4, r5, r6, r7;                               \
        threefry4(ib,       ib + 1u,  ib + 2u,  ib + 3u,  r0, r1, r2, r3);     \
        threefry4(ib + 16u, ib + 17u, ib + 18u, ib + 19u, r4, r5, r6, r7);     \
        const float f0 = (r0 < KEEP_LT9) ? 1.f : 0.f;                          \
        const float f1 = (r1 < KEEP_LT9) ? 1.f : 0.f;                          \
        const float f2 = (r2 < KEEP_LT9) ? 1.f : 0.f;                          \
        const float f3 = (r3 < KEEP_LT9) ? 1.f : 0.f;                          \
        const float f4 = (r4 < KEEP_LT9) ? 1.f : 0.f;                          \
        const float f5 = (r5 < KEEP_LT9) ? 1.f : 0.f;                          \
        const float f6 = (r6 < KEEP_LT9) ? 1.f : 0.f;                          \
        const float f7 = (r7 < KEEP_LT9) ? 1.f : 0.f;                          \
        const f32x4 zz = {0.f,0.f,0.f,0.f};                                    \
        f32x4 d0 = __builtin_amdgcn_mfma_f32_16x16x32_bf16(ka.v, qf.v, zz, 0, 0, 0); \
        f32x4 d1 = __builtin_amdgcn_mfma_f32_16x16x32_bf16(kc.v, qf.v, zz, 0, 0, 0); \
        if (TAIL) {                                                            \
            const int sv = srow + 4 * g;                                       \
            d0.x = (sv + 0  <= t_g) ? d0.x : -1e30f;                           \
            d0.y = (sv + 1  <= t_g) ? d0.y : -1e30f;                           \
            d0.z = (sv + 2  <= t_g) ? d0.z : -1e30f;                           \
            d0.w = (sv + 3  <= t_g) ? d0.w : -1e30f;                           \
            d1.x = (sv + 16 <= t_g) ? d1.x : -1e30f;                           \
            d1.y = (sv + 17 <= t_g) ? d1.y : -1e30f;                           \
            d1.z = (sv + 18 <= t_g) ? d1.z : -1e30f;                           \
            d1.w = (sv + 19 <= t_g) ? d1.w : -1e30f;                           \
        }                                                                      \
        float mx = fmaxf(fmaxf(fmaxf(d0.x, d0.y), fmaxf(d0.z, d0.w)),          \
                         fmaxf(fmaxf(d1.x, d1.y), fmaxf(d1.z, d1.w)));         \
        mx = fmaxf(mx, __shfl_xor(mx, 16));                                    \
        mx = fmaxf(mx, __shfl_xor(mx, 32));                                    \
        const bool up = mx > m + 8.0f;          /* deferred-max rescale */     \
        const float corr = up ? __expf(m - mx) : 1.0f;                         \
        m = up ? mx : m;                                                       \
        l *= corr; acc0 *= corr; acc1 *= corr;                                 \
        float p0 = __expf(d0.x - m), p1 = __expf(d0.y - m);                    \
        float p2 = __expf(d0.z - m), p3 = __expf(d0.w - m);                    \
        float p4 = __expf(d1.x - m), p5 = __expf(d1.y - m);                    \
        float p6 = __expf(d1.z - m), p7 = __expf(d1.w - m);                    \
        if (TAIL) {                                                            \
            const float alive = (srow <= t_g) ? 1.0f : 0.0f;                   \
            p0 *= alive; p1 *= alive; p2 *= alive; p3 *= alive;                \
            p4 *= alive; p5 *= alive; p6 *= alive; p7 *= alive;                \
        }                                                                      \
        float ls = ((p0 + p1) + (p2 + p3)) + ((p4 + p5) + (p6 + p7));          \
        ls += __shfl_xor(ls, 16);                                              \
        ls += __shfl_xor(ls, 32);                                              \
        l += ls;                                                               \
        const uint32_t k00 = cvt_pk_bf16(p0 * f0, p1 * f1);                    \
        const uint32_t k01 = cvt_pk_bf16(p2 * f2, p3 * f3);                    \
        const uint32_t k10 = cvt_pk_bf16(p4 * f4, p5 * f5);                    \
        const uint32_t k11 = cvt_pk_bf16(p6 * f6, p7 * f7);                    \
        const int srcA = 16 * ((g & 1) * 2) + tl;                              \
        const int srcB = srcA + 16;                                            \
        const uint32_t a0 = (uint32_t)__shfl((int)k00, srcA);                  \
        const uint32_t b0 = (uint32_t)__shfl((int)k10, srcA);                  \
        const uint32_t a1 = (uint32_t)__shfl((int)k01, srcA);                  \
        const uint32_t b1 = (uint32_t)__shfl((int)k11, srcA);                  \
        const uint32_t a2 = (uint32_t)__shfl((int)k00, srcB);                  \
        const uint32_t b2 = (uint32_t)__shfl((int)k10, srcB);                  \
        const uint32_t a3 = (uint32_t)__shfl((int)k01, srcB);                  \
        const uint32_t b3 = (uint32_t)__shfl((int)k11, srcB);                  \
        const bool hi = (g >= 2);                                              \
        pf.u[0] = hi ? b0 : a0; pf.u[1] = hi ? b1 : a1;                        \
        pf.u[2] = hi ? b2 : a2; pf.u[3] = hi ? b3 : a3;                        \
        acc0 = __builtin_amdgcn_mfma_f32_16x16x32_bf16(va.v, pf.v, acc0, 0, 0, 0); \
        acc1 = __builtin_amdgcn_mfma_f32_16x16x32_bf16(vc.v, pf.v, acc1, 0, 0, 0); \
    }

    #pragma unroll 1
    for (int win = 0; win < nwin - 1; ++win) {      // bulk: fully valid
        ATT_WINDOW(win << 7, 0)
    }
    {                                                // tail: causal
        const int s0 = (nwin - 1) << 7;
        if (s0 + slb <= t0 + thalf * 16 + 15) ATT_WINDOW(s0, 1)
    }
#undef ATT_WINDOW

    // ---- merge the 4 s-groups per t-half ----
    // slot: acc[16 t][36 c] f32 (2304B) + ml[16][2] (128B) = 2432B; 4 slots
#define SLOT(TH, S) reinterpret_cast<float*>(smem + ((TH) * 2 + (S)) * 2432)
#define PUBLISH(SB)                                                            \
    {                                                                          \
        float* sb = (SB);                                                      \
        *reinterpret_cast<float4*>(sb + tl * 36 + 4 * g)      = make_float4(acc0.x, acc0.y, acc0.z, acc0.w); \
        *reinterpret_cast<float4*>(sb + tl * 36 + 16 + 4 * g) = make_float4(acc1.x, acc1.y, acc1.z, acc1.w); \
        if (g == 0) { sb[576 + 2 * tl] = m; sb[577 + 2 * tl] = l; }            \
    }
#define CONSUME(SB)                                                            \
    {                                                                          \
        const float* sb = (SB);                                                \
        const float m2 = sb[576 + 2 * tl], l2 = sb[577 + 2 * tl];              \
        const float4 x0 = *reinterpret_cast<const float4*>(sb + tl * 36 + 4 * g); \
        const float4 x1 = *reinterpret_cast<const float4*>(sb + tl * 36 + 16 + 4 * g); \
        const float mn = fmaxf(m, m2);                                         \
        const float ca = __expf(m - mn), cb = __expf(m2 - mn);                 \
        l = l * ca + l2 * cb;                                                  \
        acc0.x = acc0.x * ca + x0.x * cb; acc0.y = acc0.y * ca + x0.y * cb;    \
        acc0.z = acc0.z * ca + x0.z * cb; acc0.w = acc0.w * ca + x0.w * cb;    \
        acc1.x = acc1.x * ca + x1.x * cb; acc1.y = acc1.y * ca + x1.y * cb;    \
        acc1.z = acc1.z * ca + x1.z * cb; acc1.w = acc1.w * ca + x1.w * cb;    \
        m = mn;                                                                \
    }
    if (sg >= 2) PUBLISH(SLOT(thalf, sg - 2))
    __syncthreads();
    if (sg < 2) CONSUME(SLOT(thalf, sg))
    __syncthreads();
    if (sg == 1) PUBLISH(SLOT(thalf, 0))
    __syncthreads();
    if (sg == 0) {
        CONSUME(SLOT(thalf, 0))
        const float inv = 1.0f / (0.8f * l);            // l,t lane-local
        float* orow = out + ((size_t)b * TTN + t_g) * CCH;
        *reinterpret_cast<float4*>(orow + 4 * g) =
            make_float4(acc0.x * inv, acc0.y * inv, acc0.z * inv, acc0.w * inv);
        *reinterpret_cast<float4*>(orow + 16 + 4 * g) =
            make_float4(acc1.x * inv, acc1.y * inv, acc1.z * inv, acc1.w * inv);
    }
#undef SLOT
#undef PUBLISH
#undef CONSUME
}

extern "C" void kernel_launch(void* const* d_in, const int* in_sizes, int n_in,
                              void* d_out, int out_size, void* d_ws, size_t ws_size,
                              hipStream_t stream) {
    const float* x  = (const float*)d_in[0];
    const float* Wq = (const float*)d_in[1];
    const float* Wk = (const float*)d_in[2];
    const float* Wv = (const float*)d_in[3];
    float* outp = (float*)d_out;

    // workspace: Qf fp32 4MiB | Kb bf16 2MiB | Vt bf16 2MiB
    float*    Qf = (float*)d_ws;
    uint16_t* Kb = (uint16_t*)((char*)d_ws + 4194304);
    uint16_t* Vt = (uint16_t*)((char*)d_ws + 6291456);

    proj_qkv<<<(BB * TTN) / 256, 256, 0, stream>>>(x, Wq, Wk, Wv, Qf, Kb, Vt);
    attn_mfma<<<1024, 512, 0, stream>>>(Qf, Kb, Vt, outp);
}